// Round 16
// baseline (150.588 us; speedup 1.0000x reference)
//
#include <hip/hip_runtime.h>
#include <hip/hip_bf16.h>

// Problem constants
#define NB    4
#define NP    12          // P1 == P == 12
#define NN_   207
#define DM    128         // d_model
#define DHID  256
#define M_TOK 9936        // NB*NP*NN_
#define M_PAD 9984        // padded to 78*128 (xT / hb / Qp row space)
#define KSPLIT 8          // j-splits (j-chunk = 32)

typedef float        f32x4 __attribute__((ext_vector_type(4)));
typedef unsigned int u32x4 __attribute__((ext_vector_type(4)));
typedef __bf16       bf16x8 __attribute__((ext_vector_type(8)));

static __device__ __forceinline__ unsigned int pk_bf2(float a, float b) {
    __hip_bfloat16 ba = __float2bfloat16(a);
    __hip_bfloat16 bb = __float2bfloat16(b);
    unsigned short ua = *reinterpret_cast<unsigned short*>(&ba);
    unsigned short ub = *reinterpret_cast<unsigned short*>(&bb);
    return (unsigned int)ua | ((unsigned int)ub << 16);
}
// hardware packed f32->bf16 (RNE), 1 instr per 2 elements (no builtin on gfx950).
static __device__ __forceinline__ unsigned int cvt_pk_bf16(float lo, float hi) {
    unsigned int r;
    asm("v_cvt_pk_bf16_f32 %0, %1, %2" : "=v"(r) : "v"(lo), "v"(hi));
    return r;
}

// ---------------- prep: W2->bf16 | transpose x->xT | meta-MFMA (h f32, Qb) ----------
// (byte-identical to rounds 13-15 — verified)
__global__ __launch_bounds__(256) void k_prep(const float* __restrict__ W2,
                                              unsigned short* __restrict__ W2b,
                                              const float* __restrict__ x,
                                              float* __restrict__ xT,
                                              const float* __restrict__ ct,
                                              const float* __restrict__ W1,
                                              const float* __restrict__ b1,
                                              const float* __restrict__ b2,
                                              float* __restrict__ hb,
                                              float* __restrict__ Qb) {
    const int t = threadIdx.x;
    const int bid = blockIdx.x;
    if (bid < 2048) {
        int i = bid * 256 + t;
        const f32x4* in = reinterpret_cast<const f32x4*>(W2);
        f32x4 v0 = in[2 * i], v1 = in[2 * i + 1];
        u32x4 o;
        o[0] = pk_bf2(v0[0], v0[1]);
        o[1] = pk_bf2(v0[2], v0[3]);
        o[2] = pk_bf2(v1[0], v1[1]);
        o[3] = pk_bf2(v1[2], v1[3]);
        reinterpret_cast<u32x4*>(W2b)[i] = o;
        return;
    }
    if (bid < 3296) {
        __shared__ float tile[32][33];
        const int b = bid - 2048;
        const int bm = b >> 2;
        const int bd = b & 3;
        const int m0 = bm * 32, d0 = bd * 32;
        #pragma unroll
        for (int i = 0; i < 4; ++i) {
            int e = i * 256 + t;
            int lm = e >> 5, ld = e & 31;
            int m = m0 + lm;
            tile[lm][ld] = (m < M_TOK) ? x[(size_t)m * DM + d0 + ld] : 0.0f;
        }
        __syncthreads();
        #pragma unroll
        for (int i = 0; i < 4; ++i) {
            int e = i * 256 + t;
            int ld = e >> 5, lm = e & 31;
            xT[(size_t)(d0 + ld) * M_PAD + m0 + lm] = tile[lm][ld];
        }
        return;
    }
    __shared__ unsigned short AB[128 * 128];
    __shared__ unsigned short WB[64 * 128];
    const int m0 = (bid - 3296) * 128;
    const int w = t >> 6, l = t & 63;
    const int lr = l & 15, g = l >> 4;

    #pragma unroll
    for (int it = 0; it < 8; ++it) {
        int r = (t >> 4) + it * 16;
        int gg = t & 15;
        int m = m0 + r;
        f32x4 a = (f32x4)(0.0f), b = (f32x4)(0.0f);
        if (m < M_TOK) {
            a = *reinterpret_cast<const f32x4*>(&ct[(size_t)m * DM + gg * 8]);
            b = *reinterpret_cast<const f32x4*>(&ct[(size_t)m * DM + gg * 8 + 4]);
        }
        u32x4 pk;
        pk[0] = pk_bf2(a[0], a[1]); pk[1] = pk_bf2(a[2], a[3]);
        pk[2] = pk_bf2(b[0], b[1]); pk[3] = pk_bf2(b[2], b[3]);
        *reinterpret_cast<u32x4*>(&AB[r * 128 + ((gg ^ (r & 7)) * 8)]) = pk;
    }

    for (int jc = 0; jc < 4; ++jc) {
        __syncthreads();
        #pragma unroll
        for (int it = 0; it < 4; ++it) {
            int r = (t >> 4) + it * 16;
            int gg = t & 15;
            const float* src = &W1[(size_t)(jc * 64 + r) * DM + gg * 8];
            f32x4 a = *reinterpret_cast<const f32x4*>(src);
            f32x4 b = *reinterpret_cast<const f32x4*>(src + 4);
            u32x4 pk;
            pk[0] = pk_bf2(a[0], a[1]); pk[1] = pk_bf2(a[2], a[3]);
            pk[2] = pk_bf2(b[0], b[1]); pk[3] = pk_bf2(b[2], b[3]);
            *reinterpret_cast<u32x4*>(&WB[r * 128 + ((gg ^ (r & 7)) * 8)]) = pk;
        }
        __syncthreads();
        f32x4 acc[2][4];
        #pragma unroll
        for (int a2 = 0; a2 < 2; ++a2)
            #pragma unroll
            for (int jf = 0; jf < 4; ++jf) acc[a2][jf] = (f32x4)(0.0f);
        #pragma unroll
        for (int ks = 0; ks < 4; ++ks) {
            bf16x8 A2[2], B4[4];
            #pragma unroll
            for (int tf = 0; tf < 2; ++tf) {
                int row = (2 * w + tf) * 16 + lr;
                A2[tf] = *reinterpret_cast<const bf16x8*>(
                    &AB[row * 128 + (((ks * 4 + g) ^ (row & 7)) * 8)]);
            }
            #pragma unroll
            for (int jf = 0; jf < 4; ++jf) {
                int row = jf * 16 + lr;
                B4[jf] = *reinterpret_cast<const bf16x8*>(
                    &WB[row * 128 + (((ks * 4 + g) ^ (row & 7)) * 8)]);
            }
            #pragma unroll
            for (int tf = 0; tf < 2; ++tf)
                #pragma unroll
                for (int jf = 0; jf < 4; ++jf)
                    acc[tf][jf] = __builtin_amdgcn_mfma_f32_16x16x32_bf16(
                        A2[tf], B4[jf], acc[tf][jf], 0, 0, 0);
        }
        #pragma unroll
        for (int jf = 0; jf < 4; ++jf) {
            int j = jc * 64 + jf * 16 + lr;
            float bv = b1[j];
            #pragma unroll
            for (int tf = 0; tf < 2; ++tf)
                #pragma unroll
                for (int rr = 0; rr < 4; ++rr) {
                    int m = m0 + (2 * w + tf) * 16 + g * 4 + rr;
                    if (m < M_TOK)
                        hb[(size_t)m * DHID + j] = fmaxf(acc[tf][jf][rr] + bv, 0.0f);
                }
        }
    }

    __syncthreads();
    #pragma unroll
    for (int it = 0; it < 8; ++it) {
        int r = (t >> 4) + it * 16;
        int gg = t & 15;
        int m = m0 + r;
        f32x4 a = (f32x4)(0.0f), b = (f32x4)(0.0f);
        if (m < M_TOK) {
            a = *reinterpret_cast<const f32x4*>(&x[(size_t)m * DM + gg * 8]);
            b = *reinterpret_cast<const f32x4*>(&x[(size_t)m * DM + gg * 8 + 4]);
        }
        u32x4 pk;
        pk[0] = pk_bf2(a[0], a[1]); pk[1] = pk_bf2(a[2], a[3]);
        pk[2] = pk_bf2(b[0], b[1]); pk[3] = pk_bf2(b[2], b[3]);
        *reinterpret_cast<u32x4*>(&AB[r * 128 + ((gg ^ (r & 7)) * 8)]) = pk;
    }
    for (int oc = 0; oc < 2; ++oc) {
        #pragma unroll
        for (int it = 0; it < 4; ++it) {
            int r = (t >> 4) + it * 16;
            int gg = t & 15;
            const float* src = &b2[(size_t)(oc * 64 + r) * DM + gg * 8];
            f32x4 a = *reinterpret_cast<const f32x4*>(src);
            f32x4 b = *reinterpret_cast<const f32x4*>(src + 4);
            u32x4 pk;
            pk[0] = pk_bf2(a[0], a[1]); pk[1] = pk_bf2(a[2], a[3]);
            pk[2] = pk_bf2(b[0], b[1]); pk[3] = pk_bf2(b[2], b[3]);
            *reinterpret_cast<u32x4*>(&WB[r * 128 + ((gg ^ (r & 7)) * 8)]) = pk;
        }
        __syncthreads();
        f32x4 acc[2][4];
        #pragma unroll
        for (int a2 = 0; a2 < 2; ++a2)
            #pragma unroll
            for (int of = 0; of < 4; ++of) acc[a2][of] = (f32x4)(0.0f);
        #pragma unroll
        for (int ks = 0; ks < 4; ++ks) {
            bf16x8 A2[2], B4[4];
            #pragma unroll
            for (int tf = 0; tf < 2; ++tf) {
                int row = (2 * w + tf) * 16 + lr;
                A2[tf] = *reinterpret_cast<const bf16x8*>(
                    &AB[row * 128 + (((ks * 4 + g) ^ (row & 7)) * 8)]);
            }
            #pragma unroll
            for (int of = 0; of < 4; ++of) {
                int row = of * 16 + lr;
                B4[of] = *reinterpret_cast<const bf16x8*>(
                    &WB[row * 128 + (((ks * 4 + g) ^ (row & 7)) * 8)]);
            }
            #pragma unroll
            for (int tf = 0; tf < 2; ++tf)
                #pragma unroll
                for (int of = 0; of < 4; ++of)
                    acc[tf][of] = __builtin_amdgcn_mfma_f32_16x16x32_bf16(
                        A2[tf], B4[of], acc[tf][of], 0, 0, 0);
        }
        #pragma unroll
        for (int of = 0; of < 4; ++of) {
            int o = oc * 64 + of * 16 + lr;
            #pragma unroll
            for (int tf = 0; tf < 2; ++tf)
                #pragma unroll
                for (int rr = 0; rr < 4; ++rr) {
                    int m = m0 + (2 * w + tf) * 16 + g * 4 + rr;
                    if (m < M_TOK) Qb[(size_t)m * DM + o] = acc[tf][of][rr];
                }
        }
        __syncthreads();
    }
}

// ---------------- bilinear GEMM, m-tile 160, wave grid 2x2 (5mf x 4of per wave) -------
// Q[m,o] = sum_{d,j} bf16(x[m,d]*h[m,j]) * bf16(W2[o*128+d, j])
// Same staged bytes/swizzle as r15; waves re-partitioned 2(m) x 2(o): per wave-step
// reads drop 12 -> 9 ds_read_b128 for the same 20 MFMA (LDS-read pipe was binding).
// Grid 63 x 8 = 504 (1.97 blocks/CU).
__global__ __launch_bounds__(256, 2) void k_gemm(const unsigned short* __restrict__ W2b,
                                                 const float* __restrict__ hbuf,
                                                 const float* __restrict__ xT,
                                                 float* __restrict__ Qp) {
    __shared__ unsigned short As[2][160 * 32];   // 10KB each
    __shared__ unsigned short Bs[2][128 * 32];   //  8KB each
    const int t = threadIdx.x;
    const int kid = blockIdx.x & 7;      // j-split -> XCD (round-robin dispatch)
    const int mb  = blockIdx.x >> 3;     // 0..62
    const int m0 = mb * 160;
    const int j0 = kid * 32;
    const int w = t >> 6, l = t & 63;
    const int wo  = w & 1;               // o-half: wave owns o in [wo*64, +64)
    const int wmi = w >> 1;              // m-half: wave owns m in [wmi*80, +80)
    const int lr = l & 15, g = l >> 4;

    // staging: base row rA = t>>2, chunk c = t&3; covers rows rA, rA+64, (rA+128 if t<128)
    const int rA = t >> 2;
    const int c  = t & 3;
    const bool has3 = (t < 128);         // wave-uniform (waves 0,1)
    const int aw = rA * 32 + ((c ^ ((rA >> 1) & 3)) * 8);   // +2048 per 64-row band

    // h fragments (constant over d)
    const float* h1p = &hbuf[(size_t)(m0 + rA) * DHID + j0 + c * 8];
    const float* h2p = &hbuf[(size_t)(m0 + 64 + rA) * DHID + j0 + c * 8];
    const f32x4 h1a = *reinterpret_cast<const f32x4*>(h1p);
    const f32x4 h1b = *reinterpret_cast<const f32x4*>(h1p + 4);
    const f32x4 h2a = *reinterpret_cast<const f32x4*>(h2p);
    const f32x4 h2b = *reinterpret_cast<const f32x4*>(h2p + 4);
    f32x4 h3a = (f32x4)(0.0f), h3b = (f32x4)(0.0f);
    if (has3) {
        const float* h3p = &hbuf[(size_t)(m0 + 128 + rA) * DHID + j0 + c * 8];
        h3a = *reinterpret_cast<const f32x4*>(h3p);
        h3b = *reinterpret_cast<const f32x4*>(h3p + 4);
    }

    f32x4 acc[5][4];
    #pragma unroll
    for (int fo = 0; fo < 5; ++fo)
        #pragma unroll
        for (int ot = 0; ot < 4; ++ot) acc[fo][ot] = (f32x4)(0.0f);

    // B sources: o-rows rA and rA+64
    const unsigned short* bp1 = W2b + (size_t)rA * 32768 + j0 + c * 8;
    const unsigned short* bp2 = bp1 + (size_t)64 * 32768;
    const float* xp = xT + m0 + rA;

    // read offsets: A row = wmi*80 + fo*16 + lr; B row = wo*64 + ot*16 + lr
    // (all bases ≡ 0 mod 8 -> read swizzle stays (g ^ ((lr>>1)&3)))
    const int rswz = (g ^ ((lr >> 1) & 3)) * 8;
    const int aBase = wmi * 2560 + lr * 32 + rswz;     // + fo*512
    const int bBase = wo * 2048 + lr * 32 + rswz;      // + ot*512

#define STAGE(BUF, BV1, BV2, XV1, XV2, XV3) do {                       \
        u32x4 a_;                                                      \
        a_[0] = cvt_pk_bf16((XV1) * h1a[0], (XV1) * h1a[1]);           \
        a_[1] = cvt_pk_bf16((XV1) * h1a[2], (XV1) * h1a[3]);           \
        a_[2] = cvt_pk_bf16((XV1) * h1b[0], (XV1) * h1b[1]);           \
        a_[3] = cvt_pk_bf16((XV1) * h1b[2], (XV1) * h1b[3]);           \
        *reinterpret_cast<u32x4*>(&As[BUF][aw]) = a_;                  \
        a_[0] = cvt_pk_bf16((XV2) * h2a[0], (XV2) * h2a[1]);           \
        a_[1] = cvt_pk_bf16((XV2) * h2a[2], (XV2) * h2a[3]);           \
        a_[2] = cvt_pk_bf16((XV2) * h2b[0], (XV2) * h2b[1]);           \
        a_[3] = cvt_pk_bf16((XV2) * h2b[2], (XV2) * h2b[3]);           \
        *reinterpret_cast<u32x4*>(&As[BUF][aw + 2048]) = a_;           \
        if (has3) {                                                    \
            a_[0] = cvt_pk_bf16((XV3) * h3a[0], (XV3) * h3a[1]);       \
            a_[1] = cvt_pk_bf16((XV3) * h3a[2], (XV3) * h3a[3]);       \
            a_[2] = cvt_pk_bf16((XV3) * h3b[0], (XV3) * h3b[1]);       \
            a_[3] = cvt_pk_bf16((XV3) * h3b[2], (XV3) * h3b[3]);       \
            *reinterpret_cast<u32x4*>(&As[BUF][aw + 4096]) = a_;       \
        }                                                              \
        *reinterpret_cast<u32x4*>(&Bs[BUF][aw]) = (BV1);               \
        *reinterpret_cast<u32x4*>(&Bs[BUF][aw + 2048]) = (BV2);        \
    } while (0)

    // prologue: stage d=0 into buf0; prefetch d=1
    {
        u32x4 bv1 = *reinterpret_cast<const u32x4*>(bp1);
        u32x4 bv2 = *reinterpret_cast<const u32x4*>(bp2);
        float x1 = xp[0], x2 = xp[64], x3 = xp[128];
        STAGE(0, bv1, bv2, x1, x2, x3);
    }
    u32x4 nb1 = *reinterpret_cast<const u32x4*>(bp1 + 256);
    u32x4 nb2 = *reinterpret_cast<const u32x4*>(bp2 + 256);
    float nx1 = xp[M_PAD], nx2 = xp[M_PAD + 64], nx3 = xp[M_PAD + 128];
    __syncthreads();

    int cur = 0;
    for (int d = 0; d < 128; ++d) {
        u32x4 bfr0 = *reinterpret_cast<const u32x4*>(&Bs[cur][bBase]);
        u32x4 bfr1 = *reinterpret_cast<const u32x4*>(&Bs[cur][bBase + 512]);
        u32x4 bfr2 = *reinterpret_cast<const u32x4*>(&Bs[cur][bBase + 1024]);
        u32x4 bfr3 = *reinterpret_cast<const u32x4*>(&Bs[cur][bBase + 1536]);
        if (d < 127) STAGE(cur ^ 1, nb1, nb2, nx1, nx2, nx3);
        if (d < 126) {
            nb1 = *reinterpret_cast<const u32x4*>(bp1 + (size_t)(d + 2) * 256);
            nb2 = *reinterpret_cast<const u32x4*>(bp2 + (size_t)(d + 2) * 256);
            const float* xq = xp + (size_t)(d + 2) * M_PAD;
            nx1 = xq[0]; nx2 = xq[64]; nx3 = xq[128];
        }
        __builtin_amdgcn_s_setprio(1);
        #pragma unroll
        for (int fo = 0; fo < 5; ++fo) {
            u32x4 afr = *reinterpret_cast<const u32x4*>(&As[cur][aBase + fo * 512]);
            asm("v_mfma_f32_16x16x32_bf16 %0, %1, %2, %0" : "+v"(acc[fo][0]) : "v"(afr), "v"(bfr0));
            asm("v_mfma_f32_16x16x32_bf16 %0, %1, %2, %0" : "+v"(acc[fo][1]) : "v"(afr), "v"(bfr1));
            asm("v_mfma_f32_16x16x32_bf16 %0, %1, %2, %0" : "+v"(acc[fo][2]) : "v"(afr), "v"(bfr2));
            asm("v_mfma_f32_16x16x32_bf16 %0, %1, %2, %0" : "+v"(acc[fo][3]) : "v"(afr), "v"(bfr3));
        }
        __builtin_amdgcn_s_setprio(0);
        __syncthreads();
        cur ^= 1;
    }
#undef STAGE

    // epilogue: D layout col(o) = lane&15, row(m) = (lane>>4)*4 + reg
    float* outp = Qp + (size_t)kid * M_PAD * DM;
    #pragma unroll
    for (int fo = 0; fo < 5; ++fo)
        #pragma unroll
        for (int ot = 0; ot < 4; ++ot)
            #pragma unroll
            for (int rr = 0; rr < 4; ++rr) {
                int m = m0 + wmi * 80 + fo * 16 + g * 4 + rr;
                int o = wo * 64 + ot * 16 + lr;
                if (m < M_TOK) outp[(size_t)m * DM + o] = acc[fo][ot][rr];
            }
}

// ---------------- attention + W_out(global-stream) + residual + layernorm ----------------
// (byte-identical to rounds 13-15 — verified)
__global__ __launch_bounds__(256) void k_attn(const float* __restrict__ Qp,
                                              const float* __restrict__ Qb,
                                              const float* __restrict__ Kenc,
                                              const float* __restrict__ Venc,
                                              const float* __restrict__ xin,
                                              const float* __restrict__ Wout,
                                              const float* __restrict__ gamma,
                                              const float* __restrict__ beta,
                                              float* __restrict__ out) {
    __shared__ float Qs[12][132];
    __shared__ float Ks[12][132];
    __shared__ float Vs[12][132];
    __shared__ float Ss[12][12][8];
    __shared__ float Os[12][132];
    const int t = threadIdx.x;
    const int b = blockIdx.x / NN_;
    const int n = blockIdx.x % NN_;

    for (int e = t; e < 384; e += 256) {
        int row = e >> 5, c4 = e & 31;
        size_t mrow = (size_t)(b * NP + row) * NN_ + n;
        f32x4 q = *reinterpret_cast<const f32x4*>(&Qb[mrow * DM + c4 * 4]);
        #pragma unroll
        for (int k = 0; k < KSPLIT; ++k)
            q += *reinterpret_cast<const f32x4*>(&Qp[((size_t)k * M_PAD + mrow) * DM + c4 * 4]);
        *reinterpret_cast<f32x4*>(&Qs[row][c4 * 4]) = q;
        *reinterpret_cast<f32x4*>(&Ks[row][c4 * 4]) =
            *reinterpret_cast<const f32x4*>(&Kenc[mrow * DM + c4 * 4]);
        *reinterpret_cast<f32x4*>(&Vs[row][c4 * 4]) =
            *reinterpret_cast<const f32x4*>(&Venc[mrow * DM + c4 * 4]);
    }
    __syncthreads();
    if (t < 144) {
        int q = t / 12, p = t % 12;
        #pragma unroll
        for (int hh = 0; hh < 8; ++hh) {
            const f32x4* qv = reinterpret_cast<const f32x4*>(&Qs[q][hh * 16]);
            const f32x4* kv = reinterpret_cast<const f32x4*>(&Ks[p][hh * 16]);
            float s = 0.0f;
            #pragma unroll
            for (int c = 0; c < 4; ++c) {
                f32x4 a = qv[c], bb = kv[c];
                s += a[0] * bb[0] + a[1] * bb[1] + a[2] * bb[2] + a[3] * bb[3];
            }
            Ss[q][p][hh] = s * 0.25f;
        }
    }
    __syncthreads();
    if (t < 96) {
        int q = t >> 3, hh = t & 7;
        float mx = -1e30f;
        #pragma unroll
        for (int p = 0; p < 12; ++p) mx = fmaxf(mx, Ss[q][p][hh]);
        float ev[12]; float sum = 0.0f;
        #pragma unroll
        for (int p = 0; p < 12; ++p) { ev[p] = __expf(Ss[q][p][hh] - mx); sum += ev[p]; }
        float inv = 1.0f / sum;
        #pragma unroll
        for (int p = 0; p < 12; ++p) Ss[q][p][hh] = ev[p] * inv;
    }
    __syncthreads();
    #pragma unroll
    for (int i = 0; i < 6; ++i) {
        int e = i * 256 + t;
        int q = e >> 7, hk = e & 127, hh = hk >> 4;
        float acc = 0.0f;
        #pragma unroll
        for (int p = 0; p < 12; ++p) acc += Ss[q][p][hh] * Vs[p][hk];
        Os[q][hk] = acc;
    }
    __syncthreads();
    {
        const int o  = t & 127;
        const int qh = (t >> 7) * 6;
        const f32x4* wrow = reinterpret_cast<const f32x4*>(&Wout[(size_t)o * DM]);
        float pacc[6] = {0, 0, 0, 0, 0, 0};
        for (int c = 0; c < 32; ++c) {
            f32x4 wv = wrow[c];
            #pragma unroll
            for (int qq = 0; qq < 6; ++qq) {
                f32x4 ov = *reinterpret_cast<const f32x4*>(&Os[qh + qq][c * 4]);
                pacc[qq] += wv[0] * ov[0] + wv[1] * ov[1] + wv[2] * ov[2] + wv[3] * ov[3];
            }
        }
        #pragma unroll
        for (int qq = 0; qq < 6; ++qq) {
            size_t mrow = (size_t)(b * NP + qh + qq) * NN_ + n;
            Qs[qh + qq][o] = pacc[qq] + xin[mrow * DM + o];
        }
    }
    __syncthreads();
    const int wv_ = t >> 6, ll = t & 63;
    for (int rq = wv_; rq < 12; rq += 4) {
        float v0 = Qs[rq][ll], v1 = Qs[rq][ll + 64];
        float s = v0 + v1, ss = v0 * v0 + v1 * v1;
        #pragma unroll
        for (int msk = 1; msk < 64; msk <<= 1) {
            s += __shfl_xor(s, msk, 64);
            ss += __shfl_xor(ss, msk, 64);
        }
        float mu = s * (1.0f / 128.0f);
        float var = ss * (1.0f / 128.0f) - mu * mu;
        float rs = rsqrtf(var + 1e-5f);
        size_t mrow = (size_t)(b * NP + rq) * NN_ + n;
        out[mrow * DM + ll]      = (v0 - mu) * rs * gamma[ll] + beta[ll];
        out[mrow * DM + ll + 64] = (v1 - mu) * rs * gamma[ll + 64] + beta[ll + 64];
    }
}

// ---------------- launcher ----------------
extern "C" void kernel_launch(void* const* d_in, const int* in_sizes, int n_in,
                              void* d_out, int out_size, void* d_ws, size_t ws_size,
                              hipStream_t stream) {
    const float* xin   = (const float*)d_in[0];
    const float* Kenc  = (const float*)d_in[1];
    const float* Venc  = (const float*)d_in[2];
    const float* ct    = (const float*)d_in[3];
    const float* W1    = (const float*)d_in[4];
    const float* b1    = (const float*)d_in[5];
    const float* W2    = (const float*)d_in[6];
    const float* b2    = (const float*)d_in[7];
    const float* Wout  = (const float*)d_in[8];
    const float* gamma = (const float*)d_in[9];
    const float* beta  = (const float*)d_in[10];
    float* out = (float*)d_out;

    char* ws = (char*)d_ws;
    unsigned short* W2b = (unsigned short*)(ws);                  //  8,388,608 B
    float* xT  = (float*)(ws + 8388608);                          //  5,111,808 B (128 x 9984)
    float* hb  = (float*)(ws + 13500416);                         // 10,223,616 B (9984 x 256)
    float* Qb  = (float*)(ws + 23724032);                         //  5,111,808 B
    float* Qp  = (float*)(ws + 28835840);                         // 40,894,464 B (8 x 9984 x 128)

    hipLaunchKernelGGL(k_prep, dim3(3374), dim3(256), 0, stream,
                       W2, W2b, xin, xT, ct, W1, b1, b2, hb, Qb);
    hipLaunchKernelGGL(k_gemm, dim3(504), dim3(256), 0, stream, W2b, hb, xT, Qp);
    hipLaunchKernelGGL(k_attn, dim3(828), dim3(256), 0, stream, Qp, Qb, Kenc, Venc,
                       xin, Wout, gamma, beta, out);
}

// Round 17
// 149.876 us; speedup vs baseline: 1.0048x; 1.0048x over previous
//
#include <hip/hip_runtime.h>
#include <hip/hip_bf16.h>

// Problem constants
#define NB    4
#define NP    12          // P1 == P == 12
#define NN_   207
#define DM    128         // d_model
#define DHID  256
#define M_TOK 9936        // NB*NP*NN_
#define M_PAD 9984        // padded to 78*128 (xT / hb / Qp row space)
#define KSPLIT 8          // j-splits (j-chunk = 32)

typedef float        f32x4 __attribute__((ext_vector_type(4)));
typedef unsigned int u32x4 __attribute__((ext_vector_type(4)));
typedef __bf16       bf16x8 __attribute__((ext_vector_type(8)));

static __device__ __forceinline__ unsigned int pk_bf2(float a, float b) {
    __hip_bfloat16 ba = __float2bfloat16(a);
    __hip_bfloat16 bb = __float2bfloat16(b);
    unsigned short ua = *reinterpret_cast<unsigned short*>(&ba);
    unsigned short ub = *reinterpret_cast<unsigned short*>(&bb);
    return (unsigned int)ua | ((unsigned int)ub << 16);
}
// hardware packed f32->bf16 (RNE), 1 instr per 2 elements (no builtin on gfx950).
static __device__ __forceinline__ unsigned int cvt_pk_bf16(float lo, float hi) {
    unsigned int r;
    asm("v_cvt_pk_bf16_f32 %0, %1, %2" : "=v"(r) : "v"(lo), "v"(hi));
    return r;
}

// ---------------- prep: W2->bf16 | transpose x->xT | meta-MFMA (h f32, Qb) ----------
// (byte-identical to rounds 13-16 — verified)
__global__ __launch_bounds__(256) void k_prep(const float* __restrict__ W2,
                                              unsigned short* __restrict__ W2b,
                                              const float* __restrict__ x,
                                              float* __restrict__ xT,
                                              const float* __restrict__ ct,
                                              const float* __restrict__ W1,
                                              const float* __restrict__ b1,
                                              const float* __restrict__ b2,
                                              float* __restrict__ hb,
                                              float* __restrict__ Qb) {
    const int t = threadIdx.x;
    const int bid = blockIdx.x;
    if (bid < 2048) {
        int i = bid * 256 + t;
        const f32x4* in = reinterpret_cast<const f32x4*>(W2);
        f32x4 v0 = in[2 * i], v1 = in[2 * i + 1];
        u32x4 o;
        o[0] = pk_bf2(v0[0], v0[1]);
        o[1] = pk_bf2(v0[2], v0[3]);
        o[2] = pk_bf2(v1[0], v1[1]);
        o[3] = pk_bf2(v1[2], v1[3]);
        reinterpret_cast<u32x4*>(W2b)[i] = o;
        return;
    }
    if (bid < 3296) {
        __shared__ float tile[32][33];
        const int b = bid - 2048;
        const int bm = b >> 2;
        const int bd = b & 3;
        const int m0 = bm * 32, d0 = bd * 32;
        #pragma unroll
        for (int i = 0; i < 4; ++i) {
            int e = i * 256 + t;
            int lm = e >> 5, ld = e & 31;
            int m = m0 + lm;
            tile[lm][ld] = (m < M_TOK) ? x[(size_t)m * DM + d0 + ld] : 0.0f;
        }
        __syncthreads();
        #pragma unroll
        for (int i = 0; i < 4; ++i) {
            int e = i * 256 + t;
            int ld = e >> 5, lm = e & 31;
            xT[(size_t)(d0 + ld) * M_PAD + m0 + lm] = tile[lm][ld];
        }
        return;
    }
    __shared__ unsigned short AB[128 * 128];
    __shared__ unsigned short WB[64 * 128];
    const int m0 = (bid - 3296) * 128;
    const int w = t >> 6, l = t & 63;
    const int lr = l & 15, g = l >> 4;

    #pragma unroll
    for (int it = 0; it < 8; ++it) {
        int r = (t >> 4) + it * 16;
        int gg = t & 15;
        int m = m0 + r;
        f32x4 a = (f32x4)(0.0f), b = (f32x4)(0.0f);
        if (m < M_TOK) {
            a = *reinterpret_cast<const f32x4*>(&ct[(size_t)m * DM + gg * 8]);
            b = *reinterpret_cast<const f32x4*>(&ct[(size_t)m * DM + gg * 8 + 4]);
        }
        u32x4 pk;
        pk[0] = pk_bf2(a[0], a[1]); pk[1] = pk_bf2(a[2], a[3]);
        pk[2] = pk_bf2(b[0], b[1]); pk[3] = pk_bf2(b[2], b[3]);
        *reinterpret_cast<u32x4*>(&AB[r * 128 + ((gg ^ (r & 7)) * 8)]) = pk;
    }

    for (int jc = 0; jc < 4; ++jc) {
        __syncthreads();
        #pragma unroll
        for (int it = 0; it < 4; ++it) {
            int r = (t >> 4) + it * 16;
            int gg = t & 15;
            const float* src = &W1[(size_t)(jc * 64 + r) * DM + gg * 8];
            f32x4 a = *reinterpret_cast<const f32x4*>(src);
            f32x4 b = *reinterpret_cast<const f32x4*>(src + 4);
            u32x4 pk;
            pk[0] = pk_bf2(a[0], a[1]); pk[1] = pk_bf2(a[2], a[3]);
            pk[2] = pk_bf2(b[0], b[1]); pk[3] = pk_bf2(b[2], b[3]);
            *reinterpret_cast<u32x4*>(&WB[r * 128 + ((gg ^ (r & 7)) * 8)]) = pk;
        }
        __syncthreads();
        f32x4 acc[2][4];
        #pragma unroll
        for (int a2 = 0; a2 < 2; ++a2)
            #pragma unroll
            for (int jf = 0; jf < 4; ++jf) acc[a2][jf] = (f32x4)(0.0f);
        #pragma unroll
        for (int ks = 0; ks < 4; ++ks) {
            bf16x8 A2[2], B4[4];
            #pragma unroll
            for (int tf = 0; tf < 2; ++tf) {
                int row = (2 * w + tf) * 16 + lr;
                A2[tf] = *reinterpret_cast<const bf16x8*>(
                    &AB[row * 128 + (((ks * 4 + g) ^ (row & 7)) * 8)]);
            }
            #pragma unroll
            for (int jf = 0; jf < 4; ++jf) {
                int row = jf * 16 + lr;
                B4[jf] = *reinterpret_cast<const bf16x8*>(
                    &WB[row * 128 + (((ks * 4 + g) ^ (row & 7)) * 8)]);
            }
            #pragma unroll
            for (int tf = 0; tf < 2; ++tf)
                #pragma unroll
                for (int jf = 0; jf < 4; ++jf)
                    acc[tf][jf] = __builtin_amdgcn_mfma_f32_16x16x32_bf16(
                        A2[tf], B4[jf], acc[tf][jf], 0, 0, 0);
        }
        #pragma unroll
        for (int jf = 0; jf < 4; ++jf) {
            int j = jc * 64 + jf * 16 + lr;
            float bv = b1[j];
            #pragma unroll
            for (int tf = 0; tf < 2; ++tf)
                #pragma unroll
                for (int rr = 0; rr < 4; ++rr) {
                    int m = m0 + (2 * w + tf) * 16 + g * 4 + rr;
                    if (m < M_TOK)
                        hb[(size_t)m * DHID + j] = fmaxf(acc[tf][jf][rr] + bv, 0.0f);
                }
        }
    }

    __syncthreads();
    #pragma unroll
    for (int it = 0; it < 8; ++it) {
        int r = (t >> 4) + it * 16;
        int gg = t & 15;
        int m = m0 + r;
        f32x4 a = (f32x4)(0.0f), b = (f32x4)(0.0f);
        if (m < M_TOK) {
            a = *reinterpret_cast<const f32x4*>(&x[(size_t)m * DM + gg * 8]);
            b = *reinterpret_cast<const f32x4*>(&x[(size_t)m * DM + gg * 8 + 4]);
        }
        u32x4 pk;
        pk[0] = pk_bf2(a[0], a[1]); pk[1] = pk_bf2(a[2], a[3]);
        pk[2] = pk_bf2(b[0], b[1]); pk[3] = pk_bf2(b[2], b[3]);
        *reinterpret_cast<u32x4*>(&AB[r * 128 + ((gg ^ (r & 7)) * 8)]) = pk;
    }
    for (int oc = 0; oc < 2; ++oc) {
        #pragma unroll
        for (int it = 0; it < 4; ++it) {
            int r = (t >> 4) + it * 16;
            int gg = t & 15;
            const float* src = &b2[(size_t)(oc * 64 + r) * DM + gg * 8];
            f32x4 a = *reinterpret_cast<const f32x4*>(src);
            f32x4 b = *reinterpret_cast<const f32x4*>(src + 4);
            u32x4 pk;
            pk[0] = pk_bf2(a[0], a[1]); pk[1] = pk_bf2(a[2], a[3]);
            pk[2] = pk_bf2(b[0], b[1]); pk[3] = pk_bf2(b[2], b[3]);
            *reinterpret_cast<u32x4*>(&WB[r * 128 + ((gg ^ (r & 7)) * 8)]) = pk;
        }
        __syncthreads();
        f32x4 acc[2][4];
        #pragma unroll
        for (int a2 = 0; a2 < 2; ++a2)
            #pragma unroll
            for (int of = 0; of < 4; ++of) acc[a2][of] = (f32x4)(0.0f);
        #pragma unroll
        for (int ks = 0; ks < 4; ++ks) {
            bf16x8 A2[2], B4[4];
            #pragma unroll
            for (int tf = 0; tf < 2; ++tf) {
                int row = (2 * w + tf) * 16 + lr;
                A2[tf] = *reinterpret_cast<const bf16x8*>(
                    &AB[row * 128 + (((ks * 4 + g) ^ (row & 7)) * 8)]);
            }
            #pragma unroll
            for (int of = 0; of < 4; ++of) {
                int row = of * 16 + lr;
                B4[of] = *reinterpret_cast<const bf16x8*>(
                    &WB[row * 128 + (((ks * 4 + g) ^ (row & 7)) * 8)]);
            }
            #pragma unroll
            for (int tf = 0; tf < 2; ++tf)
                #pragma unroll
                for (int of = 0; of < 4; ++of)
                    acc[tf][of] = __builtin_amdgcn_mfma_f32_16x16x32_bf16(
                        A2[tf], B4[of], acc[tf][of], 0, 0, 0);
        }
        #pragma unroll
        for (int of = 0; of < 4; ++of) {
            int o = oc * 64 + of * 16 + lr;
            #pragma unroll
            for (int tf = 0; tf < 2; ++tf)
                #pragma unroll
                for (int rr = 0; rr < 4; ++rr) {
                    int m = m0 + (2 * w + tf) * 16 + g * 4 + rr;
                    if (m < M_TOK) Qb[(size_t)m * DM + o] = acc[tf][of][rr];
                }
        }
        __syncthreads();
    }
}

// ---------------- bilinear GEMM, m-tile 160, 2x2 waves, d-UNROLL 2 -------------------
// Q[m,o] = sum_{d,j} bf16(x[m,d]*h[m,j]) * bf16(W2[o*128+d, j])
// Each barrier window processes TWO d-slices: 64 windows of 40 MFMA/wave instead of
// 128 windows of 20 (halves per-window fixed cost, which r14-r16 showed is binding).
// LDS 72KB dbuf (2 blocks/CU = 144KB). Same swizzle/layout per slice as r16.
__global__ __launch_bounds__(256, 2) void k_gemm(const unsigned short* __restrict__ W2b,
                                                 const float* __restrict__ hbuf,
                                                 const float* __restrict__ xT,
                                                 float* __restrict__ Qp) {
    __shared__ unsigned short As[2][10240];   // [buf][slice(5120) x2] 20KB per buf
    __shared__ unsigned short Bs[2][8192];    // [buf][slice(4096) x2] 16KB per buf
    const int t = threadIdx.x;
    const int kid = blockIdx.x & 7;      // j-split -> XCD (round-robin dispatch)
    const int mb  = blockIdx.x >> 3;     // 0..62
    const int m0 = mb * 160;
    const int j0 = kid * 32;
    const int w = t >> 6, l = t & 63;
    const int wo  = w & 1;               // o-half: wave owns o in [wo*64, +64)
    const int wmi = w >> 1;              // m-half: wave owns m in [wmi*80, +80)
    const int lr = l & 15, g = l >> 4;

    // staging: base row rA = t>>2, chunk c = t&3
    const int rA = t >> 2;
    const int c  = t & 3;
    const bool has3 = (t < 128);         // wave-uniform (waves 0,1)
    const int aw = rA * 32 + ((c ^ ((rA >> 1) & 3)) * 8);   // +2048 per 64-row band

    // h fragments (constant over d)
    const float* h1p = &hbuf[(size_t)(m0 + rA) * DHID + j0 + c * 8];
    const float* h2p = &hbuf[(size_t)(m0 + 64 + rA) * DHID + j0 + c * 8];
    const f32x4 h1a = *reinterpret_cast<const f32x4*>(h1p);
    const f32x4 h1b = *reinterpret_cast<const f32x4*>(h1p + 4);
    const f32x4 h2a = *reinterpret_cast<const f32x4*>(h2p);
    const f32x4 h2b = *reinterpret_cast<const f32x4*>(h2p + 4);
    f32x4 h3a = (f32x4)(0.0f), h3b = (f32x4)(0.0f);
    if (has3) {
        const float* h3p = &hbuf[(size_t)(m0 + 128 + rA) * DHID + j0 + c * 8];
        h3a = *reinterpret_cast<const f32x4*>(h3p);
        h3b = *reinterpret_cast<const f32x4*>(h3p + 4);
    }

    f32x4 acc[5][4];
    #pragma unroll
    for (int fo = 0; fo < 5; ++fo)
        #pragma unroll
        for (int ot = 0; ot < 4; ++ot) acc[fo][ot] = (f32x4)(0.0f);

    // B sources: o-rows rA and rA+64; element (o*128+d)*256 + j
    const unsigned short* bp1 = W2b + (size_t)rA * 32768 + j0 + c * 8;
    const unsigned short* bp2 = bp1 + (size_t)64 * 32768;
    const float* xp = xT + m0 + rA;

    // read offsets: A row = wmi*80 + fo*16 + lr (+5120 slice1); B row = wo*64 + ot*16 + lr
    const int rswz = (g ^ ((lr >> 1) & 3)) * 8;
    const int aBase = wmi * 2560 + lr * 32 + rswz;     // + fo*512
    const int bBase = wo * 2048 + lr * 32 + rswz;      // + ot*512

    // STAGE one d-slice into (BUF, slice offsets SA/SB)
#define STAGE(BUF, SA, SB, BV1, BV2, XV1, XV2, XV3) do {               \
        u32x4 a_;                                                      \
        a_[0] = cvt_pk_bf16((XV1) * h1a[0], (XV1) * h1a[1]);           \
        a_[1] = cvt_pk_bf16((XV1) * h1a[2], (XV1) * h1a[3]);           \
        a_[2] = cvt_pk_bf16((XV1) * h1b[0], (XV1) * h1b[1]);           \
        a_[3] = cvt_pk_bf16((XV1) * h1b[2], (XV1) * h1b[3]);           \
        *reinterpret_cast<u32x4*>(&As[BUF][(SA) + aw]) = a_;           \
        a_[0] = cvt_pk_bf16((XV2) * h2a[0], (XV2) * h2a[1]);           \
        a_[1] = cvt_pk_bf16((XV2) * h2a[2], (XV2) * h2a[3]);           \
        a_[2] = cvt_pk_bf16((XV2) * h2b[0], (XV2) * h2b[1]);           \
        a_[3] = cvt_pk_bf16((XV2) * h2b[2], (XV2) * h2b[3]);           \
        *reinterpret_cast<u32x4*>(&As[BUF][(SA) + aw + 2048]) = a_;    \
        if (has3) {                                                    \
            a_[0] = cvt_pk_bf16((XV3) * h3a[0], (XV3) * h3a[1]);       \
            a_[1] = cvt_pk_bf16((XV3) * h3a[2], (XV3) * h3a[3]);       \
            a_[2] = cvt_pk_bf16((XV3) * h3b[0], (XV3) * h3b[1]);       \
            a_[3] = cvt_pk_bf16((XV3) * h3b[2], (XV3) * h3b[3]);       \
            *reinterpret_cast<u32x4*>(&As[BUF][(SA) + aw + 4096]) = a_; \
        }                                                              \
        *reinterpret_cast<u32x4*>(&Bs[BUF][(SB) + aw]) = (BV1);        \
        *reinterpret_cast<u32x4*>(&Bs[BUF][(SB) + aw + 2048]) = (BV2); \
    } while (0)

    // prologue: stage window 0 (d=0 slice0, d=1 slice1) into buf0
    {
        u32x4 bv1 = *reinterpret_cast<const u32x4*>(bp1);
        u32x4 bv2 = *reinterpret_cast<const u32x4*>(bp2);
        STAGE(0, 0, 0, bv1, bv2, xp[0], xp[64], xp[128]);
        bv1 = *reinterpret_cast<const u32x4*>(bp1 + 256);
        bv2 = *reinterpret_cast<const u32x4*>(bp2 + 256);
        STAGE(0, 5120, 4096, bv1, bv2, xp[M_PAD], xp[M_PAD + 64], xp[M_PAD + 128]);
    }
    // prefetch window 1 (d=2,3) into named regs
    u32x4 nb1a = *reinterpret_cast<const u32x4*>(bp1 + 512);
    u32x4 nb2a = *reinterpret_cast<const u32x4*>(bp2 + 512);
    u32x4 nb1b = *reinterpret_cast<const u32x4*>(bp1 + 768);
    u32x4 nb2b = *reinterpret_cast<const u32x4*>(bp2 + 768);
    const float* xq2 = xp + 2 * (size_t)M_PAD;
    const float* xq3 = xp + 3 * (size_t)M_PAD;
    float nx1a = xq2[0], nx2a = xq2[64], nx3a = xq2[128];
    float nx1b = xq3[0], nx2b = xq3[64], nx3b = xq3[128];
    __syncthreads();

    int cur = 0;
    for (int wd = 0; wd < 64; ++wd) {
        // B fragments for both slices
        u32x4 bfA0 = *reinterpret_cast<const u32x4*>(&Bs[cur][bBase]);
        u32x4 bfA1 = *reinterpret_cast<const u32x4*>(&Bs[cur][bBase + 512]);
        u32x4 bfA2 = *reinterpret_cast<const u32x4*>(&Bs[cur][bBase + 1024]);
        u32x4 bfA3 = *reinterpret_cast<const u32x4*>(&Bs[cur][bBase + 1536]);
        u32x4 bfB0 = *reinterpret_cast<const u32x4*>(&Bs[cur][bBase + 4096]);
        u32x4 bfB1 = *reinterpret_cast<const u32x4*>(&Bs[cur][bBase + 4608]);
        u32x4 bfB2 = *reinterpret_cast<const u32x4*>(&Bs[cur][bBase + 5120]);
        u32x4 bfB3 = *reinterpret_cast<const u32x4*>(&Bs[cur][bBase + 5632]);
        if (wd < 63) {   // stage window wd+1 into other buffer
            STAGE(cur ^ 1, 0, 0, nb1a, nb2a, nx1a, nx2a, nx3a);
            STAGE(cur ^ 1, 5120, 4096, nb1b, nb2b, nx1b, nx2b, nx3b);
        }
        if (wd < 62) {   // prefetch window wd+2 (d = 2wd+4, 2wd+5)
            const int d4 = 2 * wd + 4, d5 = 2 * wd + 5;
            nb1a = *reinterpret_cast<const u32x4*>(bp1 + (size_t)d4 * 256);
            nb2a = *reinterpret_cast<const u32x4*>(bp2 + (size_t)d4 * 256);
            nb1b = *reinterpret_cast<const u32x4*>(bp1 + (size_t)d5 * 256);
            nb2b = *reinterpret_cast<const u32x4*>(bp2 + (size_t)d5 * 256);
            const float* xq4 = xp + (size_t)d4 * M_PAD;
            const float* xq5 = xp + (size_t)d5 * M_PAD;
            nx1a = xq4[0]; nx2a = xq4[64]; nx3a = xq4[128];
            nx1b = xq5[0]; nx2b = xq5[64]; nx3b = xq5[128];
        }
        __builtin_amdgcn_s_setprio(1);
        #pragma unroll
        for (int fo = 0; fo < 5; ++fo) {
            u32x4 afr = *reinterpret_cast<const u32x4*>(&As[cur][aBase + fo * 512]);
            asm("v_mfma_f32_16x16x32_bf16 %0, %1, %2, %0" : "+v"(acc[fo][0]) : "v"(afr), "v"(bfA0));
            asm("v_mfma_f32_16x16x32_bf16 %0, %1, %2, %0" : "+v"(acc[fo][1]) : "v"(afr), "v"(bfA1));
            asm("v_mfma_f32_16x16x32_bf16 %0, %1, %2, %0" : "+v"(acc[fo][2]) : "v"(afr), "v"(bfA2));
            asm("v_mfma_f32_16x16x32_bf16 %0, %1, %2, %0" : "+v"(acc[fo][3]) : "v"(afr), "v"(bfA3));
        }
        #pragma unroll
        for (int fo = 0; fo < 5; ++fo) {
            u32x4 afr = *reinterpret_cast<const u32x4*>(&As[cur][aBase + 5120 + fo * 512]);
            asm("v_mfma_f32_16x16x32_bf16 %0, %1, %2, %0" : "+v"(acc[fo][0]) : "v"(afr), "v"(bfB0));
            asm("v_mfma_f32_16x16x32_bf16 %0, %1, %2, %0" : "+v"(acc[fo][1]) : "v"(afr), "v"(bfB1));
            asm("v_mfma_f32_16x16x32_bf16 %0, %1, %2, %0" : "+v"(acc[fo][2]) : "v"(afr), "v"(bfB2));
            asm("v_mfma_f32_16x16x32_bf16 %0, %1, %2, %0" : "+v"(acc[fo][3]) : "v"(afr), "v"(bfB3));
        }
        __builtin_amdgcn_s_setprio(0);
        __syncthreads();
        cur ^= 1;
    }
#undef STAGE

    // epilogue: D layout col(o) = lane&15, row(m) = (lane>>4)*4 + reg
    float* outp = Qp + (size_t)kid * M_PAD * DM;
    #pragma unroll
    for (int fo = 0; fo < 5; ++fo)
        #pragma unroll
        for (int ot = 0; ot < 4; ++ot)
            #pragma unroll
            for (int rr = 0; rr < 4; ++rr) {
                int m = m0 + wmi * 80 + fo * 16 + g * 4 + rr;
                int o = wo * 64 + ot * 16 + lr;
                if (m < M_TOK) outp[(size_t)m * DM + o] = acc[fo][ot][rr];
            }
}

// ---------------- attention + W_out(global-stream) + residual + layernorm ----------------
// (byte-identical to rounds 13-16 — verified)
__global__ __launch_bounds__(256) void k_attn(const float* __restrict__ Qp,
                                              const float* __restrict__ Qb,
                                              const float* __restrict__ Kenc,
                                              const float* __restrict__ Venc,
                                              const float* __restrict__ xin,
                                              const float* __restrict__ Wout,
                                              const float* __restrict__ gamma,
                                              const float* __restrict__ beta,
                                              float* __restrict__ out) {
    __shared__ float Qs[12][132];
    __shared__ float Ks[12][132];
    __shared__ float Vs[12][132];
    __shared__ float Ss[12][12][8];
    __shared__ float Os[12][132];
    const int t = threadIdx.x;
    const int b = blockIdx.x / NN_;
    const int n = blockIdx.x % NN_;

    for (int e = t; e < 384; e += 256) {
        int row = e >> 5, c4 = e & 31;
        size_t mrow = (size_t)(b * NP + row) * NN_ + n;
        f32x4 q = *reinterpret_cast<const f32x4*>(&Qb[mrow * DM + c4 * 4]);
        #pragma unroll
        for (int k = 0; k < KSPLIT; ++k)
            q += *reinterpret_cast<const f32x4*>(&Qp[((size_t)k * M_PAD + mrow) * DM + c4 * 4]);
        *reinterpret_cast<f32x4*>(&Qs[row][c4 * 4]) = q;
        *reinterpret_cast<f32x4*>(&Ks[row][c4 * 4]) =
            *reinterpret_cast<const f32x4*>(&Kenc[mrow * DM + c4 * 4]);
        *reinterpret_cast<f32x4*>(&Vs[row][c4 * 4]) =
            *reinterpret_cast<const f32x4*>(&Venc[mrow * DM + c4 * 4]);
    }
    __syncthreads();
    if (t < 144) {
        int q = t / 12, p = t % 12;
        #pragma unroll
        for (int hh = 0; hh < 8; ++hh) {
            const f32x4* qv = reinterpret_cast<const f32x4*>(&Qs[q][hh * 16]);
            const f32x4* kv = reinterpret_cast<const f32x4*>(&Ks[p][hh * 16]);
            float s = 0.0f;
            #pragma unroll
            for (int c = 0; c < 4; ++c) {
                f32x4 a = qv[c], bb = kv[c];
                s += a[0] * bb[0] + a[1] * bb[1] + a[2] * bb[2] + a[3] * bb[3];
            }
            Ss[q][p][hh] = s * 0.25f;
        }
    }
    __syncthreads();
    if (t < 96) {
        int q = t >> 3, hh = t & 7;
        float mx = -1e30f;
        #pragma unroll
        for (int p = 0; p < 12; ++p) mx = fmaxf(mx, Ss[q][p][hh]);
        float ev[12]; float sum = 0.0f;
        #pragma unroll
        for (int p = 0; p < 12; ++p) { ev[p] = __expf(Ss[q][p][hh] - mx); sum += ev[p]; }
        float inv = 1.0f / sum;
        #pragma unroll
        for (int p = 0; p < 12; ++p) Ss[q][p][hh] = ev[p] * inv;
    }
    __syncthreads();
    #pragma unroll
    for (int i = 0; i < 6; ++i) {
        int e = i * 256 + t;
        int q = e >> 7, hk = e & 127, hh = hk >> 4;
        float acc = 0.0f;
        #pragma unroll
        for (int p = 0; p < 12; ++p) acc += Ss[q][p][hh] * Vs[p][hk];
        Os[q][hk] = acc;
    }
    __syncthreads();
    {
        const int o  = t & 127;
        const int qh = (t >> 7) * 6;
        const f32x4* wrow = reinterpret_cast<const f32x4*>(&Wout[(size_t)o * DM]);
        float pacc[6] = {0, 0, 0, 0, 0, 0};
        for (int c = 0; c < 32; ++c) {
            f32x4 wv = wrow[c];
            #pragma unroll
            for (int qq = 0; qq < 6; ++qq) {
                f32x4 ov = *reinterpret_cast<const f32x4*>(&Os[qh + qq][c * 4]);
                pacc[qq] += wv[0] * ov[0] + wv[1] * ov[1] + wv[2] * ov[2] + wv[3] * ov[3];
            }
        }
        #pragma unroll
        for (int qq = 0; qq < 6; ++qq) {
            size_t mrow = (size_t)(b * NP + qh + qq) * NN_ + n;
            Qs[qh + qq][o] = pacc[qq] + xin[mrow * DM + o];
        }
    }
    __syncthreads();
    const int wv_ = t >> 6, ll = t & 63;
    for (int rq = wv_; rq < 12; rq += 4) {
        float v0 = Qs[rq][ll], v1 = Qs[rq][ll + 64];
        float s = v0 + v1, ss = v0 * v0 + v1 * v1;
        #pragma unroll
        for (int msk = 1; msk < 64; msk <<= 1) {
            s += __shfl_xor(s, msk, 64);
            ss += __shfl_xor(ss, msk, 64);
        }
        float mu = s * (1.0f / 128.0f);
        float var = ss * (1.0f / 128.0f) - mu * mu;
        float rs = rsqrtf(var + 1e-5f);
        size_t mrow = (size_t)(b * NP + rq) * NN_ + n;
        out[mrow * DM + ll]      = (v0 - mu) * rs * gamma[ll] + beta[ll];
        out[mrow * DM + ll + 64] = (v1 - mu) * rs * gamma[ll + 64] + beta[ll + 64];
    }
}

// ---------------- launcher ----------------
extern "C" void kernel_launch(void* const* d_in, const int* in_sizes, int n_in,
                              void* d_out, int out_size, void* d_ws, size_t ws_size,
                              hipStream_t stream) {
    const float* xin   = (const float*)d_in[0];
    const float* Kenc  = (const float*)d_in[1];
    const float* Venc  = (const float*)d_in[2];
    const float* ct    = (const float*)d_in[3];
    const float* W1    = (const float*)d_in[4];
    const float* b1    = (const float*)d_in[5];
    const float* W2    = (const float*)d_in[6];
    const float* b2    = (const float*)d_in[7];
    const float* Wout  = (const float*)d_in[8];
    const float* gamma = (const float*)d_in[9];
    const float* beta  = (const float*)d_in[10];
    float* out = (float*)d_out;

    char* ws = (char*)d_ws;
    unsigned short* W2b = (unsigned short*)(ws);                  //  8,388,608 B
    float* xT  = (float*)(ws + 8388608);                          //  5,111,808 B (128 x 9984)
    float* hb  = (float*)(ws + 13500416);                         // 10,223,616 B (9984 x 256)
    float* Qb  = (float*)(ws + 23724032);                         //  5,111,808 B
    float* Qp  = (float*)(ws + 28835840);                         // 40,894,464 B (8 x 9984 x 128)

    hipLaunchKernelGGL(k_prep, dim3(3374), dim3(256), 0, stream,
                       W2, W2b, xin, xT, ct, W1, b1, b2, hb, Qb);
    hipLaunchKernelGGL(k_gemm, dim3(504), dim3(256), 0, stream, W2b, hb, xT, Qp);
    hipLaunchKernelGGL(k_attn, dim3(828), dim3(256), 0, stream, Qp, Qb, Kenc, Venc,
                       xin, Wout, gamma, beta, out);
}

// Round 18
// 147.914 us; speedup vs baseline: 1.0181x; 1.0133x over previous
//
#include <hip/hip_runtime.h>
#include <hip/hip_bf16.h>

// Problem constants
#define NB    4
#define NP    12          // P1 == P == 12
#define NN_   207
#define DM    128         // d_model
#define DHID  256
#define M_TOK 9936        // NB*NP*NN_
#define M_PAD 9984        // padded to 78*128 (xT / hb / Qp row space)
#define KSPLIT 8          // j-splits (j-chunk = 32)

typedef float        f32x4 __attribute__((ext_vector_type(4)));
typedef unsigned int u32x4 __attribute__((ext_vector_type(4)));
typedef __bf16       bf16x8 __attribute__((ext_vector_type(8)));

static __device__ __forceinline__ unsigned int pk_bf2(float a, float b) {
    __hip_bfloat16 ba = __float2bfloat16(a);
    __hip_bfloat16 bb = __float2bfloat16(b);
    unsigned short ua = *reinterpret_cast<unsigned short*>(&ba);
    unsigned short ub = *reinterpret_cast<unsigned short*>(&bb);
    return (unsigned int)ua | ((unsigned int)ub << 16);
}
// hardware packed f32->bf16 (RNE), 1 instr per 2 elements (no builtin on gfx950).
static __device__ __forceinline__ unsigned int cvt_pk_bf16(float lo, float hi) {
    unsigned int r;
    asm("v_cvt_pk_bf16_f32 %0, %1, %2" : "=v"(r) : "v"(lo), "v"(hi));
    return r;
}

// ---------------- prep: W2->bf16 | transpose x->xT | meta-MFMA (h f32, Qb) ----------
// (byte-identical to rounds 13-17 — verified)
__global__ __launch_bounds__(256) void k_prep(const float* __restrict__ W2,
                                              unsigned short* __restrict__ W2b,
                                              const float* __restrict__ x,
                                              float* __restrict__ xT,
                                              const float* __restrict__ ct,
                                              const float* __restrict__ W1,
                                              const float* __restrict__ b1,
                                              const float* __restrict__ b2,
                                              float* __restrict__ hb,
                                              float* __restrict__ Qb) {
    const int t = threadIdx.x;
    const int bid = blockIdx.x;
    if (bid < 2048) {
        int i = bid * 256 + t;
        const f32x4* in = reinterpret_cast<const f32x4*>(W2);
        f32x4 v0 = in[2 * i], v1 = in[2 * i + 1];
        u32x4 o;
        o[0] = pk_bf2(v0[0], v0[1]);
        o[1] = pk_bf2(v0[2], v0[3]);
        o[2] = pk_bf2(v1[0], v1[1]);
        o[3] = pk_bf2(v1[2], v1[3]);
        reinterpret_cast<u32x4*>(W2b)[i] = o;
        return;
    }
    if (bid < 3296) {
        __shared__ float tile[32][33];
        const int b = bid - 2048;
        const int bm = b >> 2;
        const int bd = b & 3;
        const int m0 = bm * 32, d0 = bd * 32;
        #pragma unroll
        for (int i = 0; i < 4; ++i) {
            int e = i * 256 + t;
            int lm = e >> 5, ld = e & 31;
            int m = m0 + lm;
            tile[lm][ld] = (m < M_TOK) ? x[(size_t)m * DM + d0 + ld] : 0.0f;
        }
        __syncthreads();
        #pragma unroll
        for (int i = 0; i < 4; ++i) {
            int e = i * 256 + t;
            int ld = e >> 5, lm = e & 31;
            xT[(size_t)(d0 + ld) * M_PAD + m0 + lm] = tile[lm][ld];
        }
        return;
    }
    __shared__ unsigned short AB[128 * 128];
    __shared__ unsigned short WB[64 * 128];
    const int m0 = (bid - 3296) * 128;
    const int w = t >> 6, l = t & 63;
    const int lr = l & 15, g = l >> 4;

    #pragma unroll
    for (int it = 0; it < 8; ++it) {
        int r = (t >> 4) + it * 16;
        int gg = t & 15;
        int m = m0 + r;
        f32x4 a = (f32x4)(0.0f), b = (f32x4)(0.0f);
        if (m < M_TOK) {
            a = *reinterpret_cast<const f32x4*>(&ct[(size_t)m * DM + gg * 8]);
            b = *reinterpret_cast<const f32x4*>(&ct[(size_t)m * DM + gg * 8 + 4]);
        }
        u32x4 pk;
        pk[0] = pk_bf2(a[0], a[1]); pk[1] = pk_bf2(a[2], a[3]);
        pk[2] = pk_bf2(b[0], b[1]); pk[3] = pk_bf2(b[2], b[3]);
        *reinterpret_cast<u32x4*>(&AB[r * 128 + ((gg ^ (r & 7)) * 8)]) = pk;
    }

    for (int jc = 0; jc < 4; ++jc) {
        __syncthreads();
        #pragma unroll
        for (int it = 0; it < 4; ++it) {
            int r = (t >> 4) + it * 16;
            int gg = t & 15;
            const float* src = &W1[(size_t)(jc * 64 + r) * DM + gg * 8];
            f32x4 a = *reinterpret_cast<const f32x4*>(src);
            f32x4 b = *reinterpret_cast<const f32x4*>(src + 4);
            u32x4 pk;
            pk[0] = pk_bf2(a[0], a[1]); pk[1] = pk_bf2(a[2], a[3]);
            pk[2] = pk_bf2(b[0], b[1]); pk[3] = pk_bf2(b[2], b[3]);
            *reinterpret_cast<u32x4*>(&WB[r * 128 + ((gg ^ (r & 7)) * 8)]) = pk;
        }
        __syncthreads();
        f32x4 acc[2][4];
        #pragma unroll
        for (int a2 = 0; a2 < 2; ++a2)
            #pragma unroll
            for (int jf = 0; jf < 4; ++jf) acc[a2][jf] = (f32x4)(0.0f);
        #pragma unroll
        for (int ks = 0; ks < 4; ++ks) {
            bf16x8 A2[2], B4[4];
            #pragma unroll
            for (int tf = 0; tf < 2; ++tf) {
                int row = (2 * w + tf) * 16 + lr;
                A2[tf] = *reinterpret_cast<const bf16x8*>(
                    &AB[row * 128 + (((ks * 4 + g) ^ (row & 7)) * 8)]);
            }
            #pragma unroll
            for (int jf = 0; jf < 4; ++jf) {
                int row = jf * 16 + lr;
                B4[jf] = *reinterpret_cast<const bf16x8*>(
                    &WB[row * 128 + (((ks * 4 + g) ^ (row & 7)) * 8)]);
            }
            #pragma unroll
            for (int tf = 0; tf < 2; ++tf)
                #pragma unroll
                for (int jf = 0; jf < 4; ++jf)
                    acc[tf][jf] = __builtin_amdgcn_mfma_f32_16x16x32_bf16(
                        A2[tf], B4[jf], acc[tf][jf], 0, 0, 0);
        }
        #pragma unroll
        for (int jf = 0; jf < 4; ++jf) {
            int j = jc * 64 + jf * 16 + lr;
            float bv = b1[j];
            #pragma unroll
            for (int tf = 0; tf < 2; ++tf)
                #pragma unroll
                for (int rr = 0; rr < 4; ++rr) {
                    int m = m0 + (2 * w + tf) * 16 + g * 4 + rr;
                    if (m < M_TOK)
                        hb[(size_t)m * DHID + j] = fmaxf(acc[tf][jf][rr] + bv, 0.0f);
                }
        }
    }

    __syncthreads();
    #pragma unroll
    for (int it = 0; it < 8; ++it) {
        int r = (t >> 4) + it * 16;
        int gg = t & 15;
        int m = m0 + r;
        f32x4 a = (f32x4)(0.0f), b = (f32x4)(0.0f);
        if (m < M_TOK) {
            a = *reinterpret_cast<const f32x4*>(&x[(size_t)m * DM + gg * 8]);
            b = *reinterpret_cast<const f32x4*>(&x[(size_t)m * DM + gg * 8 + 4]);
        }
        u32x4 pk;
        pk[0] = pk_bf2(a[0], a[1]); pk[1] = pk_bf2(a[2], a[3]);
        pk[2] = pk_bf2(b[0], b[1]); pk[3] = pk_bf2(b[2], b[3]);
        *reinterpret_cast<u32x4*>(&AB[r * 128 + ((gg ^ (r & 7)) * 8)]) = pk;
    }
    for (int oc = 0; oc < 2; ++oc) {
        #pragma unroll
        for (int it = 0; it < 4; ++it) {
            int r = (t >> 4) + it * 16;
            int gg = t & 15;
            const float* src = &b2[(size_t)(oc * 64 + r) * DM + gg * 8];
            f32x4 a = *reinterpret_cast<const f32x4*>(src);
            f32x4 b = *reinterpret_cast<const f32x4*>(src + 4);
            u32x4 pk;
            pk[0] = pk_bf2(a[0], a[1]); pk[1] = pk_bf2(a[2], a[3]);
            pk[2] = pk_bf2(b[0], b[1]); pk[3] = pk_bf2(b[2], b[3]);
            *reinterpret_cast<u32x4*>(&WB[r * 128 + ((gg ^ (r & 7)) * 8)]) = pk;
        }
        __syncthreads();
        f32x4 acc[2][4];
        #pragma unroll
        for (int a2 = 0; a2 < 2; ++a2)
            #pragma unroll
            for (int of = 0; of < 4; ++of) acc[a2][of] = (f32x4)(0.0f);
        #pragma unroll
        for (int ks = 0; ks < 4; ++ks) {
            bf16x8 A2[2], B4[4];
            #pragma unroll
            for (int tf = 0; tf < 2; ++tf) {
                int row = (2 * w + tf) * 16 + lr;
                A2[tf] = *reinterpret_cast<const bf16x8*>(
                    &AB[row * 128 + (((ks * 4 + g) ^ (row & 7)) * 8)]);
            }
            #pragma unroll
            for (int of = 0; of < 4; ++of) {
                int row = of * 16 + lr;
                B4[of] = *reinterpret_cast<const bf16x8*>(
                    &WB[row * 128 + (((ks * 4 + g) ^ (row & 7)) * 8)]);
            }
            #pragma unroll
            for (int tf = 0; tf < 2; ++tf)
                #pragma unroll
                for (int of = 0; of < 4; ++of)
                    acc[tf][of] = __builtin_amdgcn_mfma_f32_16x16x32_bf16(
                        A2[tf], B4[of], acc[tf][of], 0, 0, 0);
        }
        #pragma unroll
        for (int of = 0; of < 4; ++of) {
            int o = oc * 64 + of * 16 + lr;
            #pragma unroll
            for (int tf = 0; tf < 2; ++tf)
                #pragma unroll
                for (int rr = 0; rr < 4; ++rr) {
                    int m = m0 + (2 * w + tf) * 16 + g * 4 + rr;
                    if (m < M_TOK) Qb[(size_t)m * DM + o] = acc[tf][of][rr];
                }
        }
        __syncthreads();
    }
}

// ---------------- bilinear GEMM, m-tile 160, 2x2 waves, d-unroll 2, bf16 partials -----
// (r17 structure — verified; epilogue now writes bf16 Qp partials: halves write traffic)
__global__ __launch_bounds__(256, 2) void k_gemm(const unsigned short* __restrict__ W2b,
                                                 const float* __restrict__ hbuf,
                                                 const float* __restrict__ xT,
                                                 unsigned short* __restrict__ Qp) {
    __shared__ unsigned short As[2][10240];   // [buf][slice(5120) x2] 20KB per buf
    __shared__ unsigned short Bs[2][8192];    // [buf][slice(4096) x2] 16KB per buf
    const int t = threadIdx.x;
    const int kid = blockIdx.x & 7;      // j-split -> XCD (round-robin dispatch)
    const int mb  = blockIdx.x >> 3;     // 0..62
    const int m0 = mb * 160;
    const int j0 = kid * 32;
    const int w = t >> 6, l = t & 63;
    const int wo  = w & 1;               // o-half: wave owns o in [wo*64, +64)
    const int wmi = w >> 1;              // m-half: wave owns m in [wmi*80, +80)
    const int lr = l & 15, g = l >> 4;

    // staging: base row rA = t>>2, chunk c = t&3
    const int rA = t >> 2;
    const int c  = t & 3;
    const bool has3 = (t < 128);         // wave-uniform (waves 0,1)
    const int aw = rA * 32 + ((c ^ ((rA >> 1) & 3)) * 8);   // +2048 per 64-row band

    // h fragments (constant over d)
    const float* h1p = &hbuf[(size_t)(m0 + rA) * DHID + j0 + c * 8];
    const float* h2p = &hbuf[(size_t)(m0 + 64 + rA) * DHID + j0 + c * 8];
    const f32x4 h1a = *reinterpret_cast<const f32x4*>(h1p);
    const f32x4 h1b = *reinterpret_cast<const f32x4*>(h1p + 4);
    const f32x4 h2a = *reinterpret_cast<const f32x4*>(h2p);
    const f32x4 h2b = *reinterpret_cast<const f32x4*>(h2p + 4);
    f32x4 h3a = (f32x4)(0.0f), h3b = (f32x4)(0.0f);
    if (has3) {
        const float* h3p = &hbuf[(size_t)(m0 + 128 + rA) * DHID + j0 + c * 8];
        h3a = *reinterpret_cast<const f32x4*>(h3p);
        h3b = *reinterpret_cast<const f32x4*>(h3p + 4);
    }

    f32x4 acc[5][4];
    #pragma unroll
    for (int fo = 0; fo < 5; ++fo)
        #pragma unroll
        for (int ot = 0; ot < 4; ++ot) acc[fo][ot] = (f32x4)(0.0f);

    // B sources: o-rows rA and rA+64; element (o*128+d)*256 + j
    const unsigned short* bp1 = W2b + (size_t)rA * 32768 + j0 + c * 8;
    const unsigned short* bp2 = bp1 + (size_t)64 * 32768;
    const float* xp = xT + m0 + rA;

    // read offsets: A row = wmi*80 + fo*16 + lr (+5120 slice1); B row = wo*64 + ot*16 + lr
    const int rswz = (g ^ ((lr >> 1) & 3)) * 8;
    const int aBase = wmi * 2560 + lr * 32 + rswz;     // + fo*512
    const int bBase = wo * 2048 + lr * 32 + rswz;      // + ot*512

    // STAGE one d-slice into (BUF, slice offsets SA/SB)
#define STAGE(BUF, SA, SB, BV1, BV2, XV1, XV2, XV3) do {               \
        u32x4 a_;                                                      \
        a_[0] = cvt_pk_bf16((XV1) * h1a[0], (XV1) * h1a[1]);           \
        a_[1] = cvt_pk_bf16((XV1) * h1a[2], (XV1) * h1a[3]);           \
        a_[2] = cvt_pk_bf16((XV1) * h1b[0], (XV1) * h1b[1]);           \
        a_[3] = cvt_pk_bf16((XV1) * h1b[2], (XV1) * h1b[3]);           \
        *reinterpret_cast<u32x4*>(&As[BUF][(SA) + aw]) = a_;           \
        a_[0] = cvt_pk_bf16((XV2) * h2a[0], (XV2) * h2a[1]);           \
        a_[1] = cvt_pk_bf16((XV2) * h2a[2], (XV2) * h2a[3]);           \
        a_[2] = cvt_pk_bf16((XV2) * h2b[0], (XV2) * h2b[1]);           \
        a_[3] = cvt_pk_bf16((XV2) * h2b[2], (XV2) * h2b[3]);           \
        *reinterpret_cast<u32x4*>(&As[BUF][(SA) + aw + 2048]) = a_;    \
        if (has3) {                                                    \
            a_[0] = cvt_pk_bf16((XV3) * h3a[0], (XV3) * h3a[1]);       \
            a_[1] = cvt_pk_bf16((XV3) * h3a[2], (XV3) * h3a[3]);       \
            a_[2] = cvt_pk_bf16((XV3) * h3b[0], (XV3) * h3b[1]);       \
            a_[3] = cvt_pk_bf16((XV3) * h3b[2], (XV3) * h3b[3]);       \
            *reinterpret_cast<u32x4*>(&As[BUF][(SA) + aw + 4096]) = a_; \
        }                                                              \
        *reinterpret_cast<u32x4*>(&Bs[BUF][(SB) + aw]) = (BV1);        \
        *reinterpret_cast<u32x4*>(&Bs[BUF][(SB) + aw + 2048]) = (BV2); \
    } while (0)

    // prologue: stage window 0 (d=0 slice0, d=1 slice1) into buf0
    {
        u32x4 bv1 = *reinterpret_cast<const u32x4*>(bp1);
        u32x4 bv2 = *reinterpret_cast<const u32x4*>(bp2);
        STAGE(0, 0, 0, bv1, bv2, xp[0], xp[64], xp[128]);
        bv1 = *reinterpret_cast<const u32x4*>(bp1 + 256);
        bv2 = *reinterpret_cast<const u32x4*>(bp2 + 256);
        STAGE(0, 5120, 4096, bv1, bv2, xp[M_PAD], xp[M_PAD + 64], xp[M_PAD + 128]);
    }
    // prefetch window 1 (d=2,3) into named regs
    u32x4 nb1a = *reinterpret_cast<const u32x4*>(bp1 + 512);
    u32x4 nb2a = *reinterpret_cast<const u32x4*>(bp2 + 512);
    u32x4 nb1b = *reinterpret_cast<const u32x4*>(bp1 + 768);
    u32x4 nb2b = *reinterpret_cast<const u32x4*>(bp2 + 768);
    const float* xq2 = xp + 2 * (size_t)M_PAD;
    const float* xq3 = xp + 3 * (size_t)M_PAD;
    float nx1a = xq2[0], nx2a = xq2[64], nx3a = xq2[128];
    float nx1b = xq3[0], nx2b = xq3[64], nx3b = xq3[128];
    __syncthreads();

    int cur = 0;
    for (int wd = 0; wd < 64; ++wd) {
        // B fragments for both slices
        u32x4 bfA0 = *reinterpret_cast<const u32x4*>(&Bs[cur][bBase]);
        u32x4 bfA1 = *reinterpret_cast<const u32x4*>(&Bs[cur][bBase + 512]);
        u32x4 bfA2 = *reinterpret_cast<const u32x4*>(&Bs[cur][bBase + 1024]);
        u32x4 bfA3 = *reinterpret_cast<const u32x4*>(&Bs[cur][bBase + 1536]);
        u32x4 bfB0 = *reinterpret_cast<const u32x4*>(&Bs[cur][bBase + 4096]);
        u32x4 bfB1 = *reinterpret_cast<const u32x4*>(&Bs[cur][bBase + 4608]);
        u32x4 bfB2 = *reinterpret_cast<const u32x4*>(&Bs[cur][bBase + 5120]);
        u32x4 bfB3 = *reinterpret_cast<const u32x4*>(&Bs[cur][bBase + 5632]);
        if (wd < 63) {   // stage window wd+1 into other buffer
            STAGE(cur ^ 1, 0, 0, nb1a, nb2a, nx1a, nx2a, nx3a);
            STAGE(cur ^ 1, 5120, 4096, nb1b, nb2b, nx1b, nx2b, nx3b);
        }
        if (wd < 62) {   // prefetch window wd+2 (d = 2wd+4, 2wd+5)
            const int d4 = 2 * wd + 4, d5 = 2 * wd + 5;
            nb1a = *reinterpret_cast<const u32x4*>(bp1 + (size_t)d4 * 256);
            nb2a = *reinterpret_cast<const u32x4*>(bp2 + (size_t)d4 * 256);
            nb1b = *reinterpret_cast<const u32x4*>(bp1 + (size_t)d5 * 256);
            nb2b = *reinterpret_cast<const u32x4*>(bp2 + (size_t)d5 * 256);
            const float* xq4 = xp + (size_t)d4 * M_PAD;
            const float* xq5 = xp + (size_t)d5 * M_PAD;
            nx1a = xq4[0]; nx2a = xq4[64]; nx3a = xq4[128];
            nx1b = xq5[0]; nx2b = xq5[64]; nx3b = xq5[128];
        }
        __builtin_amdgcn_s_setprio(1);
        #pragma unroll
        for (int fo = 0; fo < 5; ++fo) {
            u32x4 afr = *reinterpret_cast<const u32x4*>(&As[cur][aBase + fo * 512]);
            asm("v_mfma_f32_16x16x32_bf16 %0, %1, %2, %0" : "+v"(acc[fo][0]) : "v"(afr), "v"(bfA0));
            asm("v_mfma_f32_16x16x32_bf16 %0, %1, %2, %0" : "+v"(acc[fo][1]) : "v"(afr), "v"(bfA1));
            asm("v_mfma_f32_16x16x32_bf16 %0, %1, %2, %0" : "+v"(acc[fo][2]) : "v"(afr), "v"(bfA2));
            asm("v_mfma_f32_16x16x32_bf16 %0, %1, %2, %0" : "+v"(acc[fo][3]) : "v"(afr), "v"(bfA3));
        }
        #pragma unroll
        for (int fo = 0; fo < 5; ++fo) {
            u32x4 afr = *reinterpret_cast<const u32x4*>(&As[cur][aBase + 5120 + fo * 512]);
            asm("v_mfma_f32_16x16x32_bf16 %0, %1, %2, %0" : "+v"(acc[fo][0]) : "v"(afr), "v"(bfB0));
            asm("v_mfma_f32_16x16x32_bf16 %0, %1, %2, %0" : "+v"(acc[fo][1]) : "v"(afr), "v"(bfB1));
            asm("v_mfma_f32_16x16x32_bf16 %0, %1, %2, %0" : "+v"(acc[fo][2]) : "v"(afr), "v"(bfB2));
            asm("v_mfma_f32_16x16x32_bf16 %0, %1, %2, %0" : "+v"(acc[fo][3]) : "v"(afr), "v"(bfB3));
        }
        __builtin_amdgcn_s_setprio(0);
        __syncthreads();
        cur ^= 1;
    }
#undef STAGE

    // epilogue: D layout col(o) = lane&15, row(m) = (lane>>4)*4 + reg; write bf16
    unsigned short* outp = Qp + (size_t)kid * M_PAD * DM;
    #pragma unroll
    for (int fo = 0; fo < 5; ++fo)
        #pragma unroll
        for (int ot = 0; ot < 4; ++ot)
            #pragma unroll
            for (int rr = 0; rr < 4; ++rr) {
                int m = m0 + wmi * 80 + fo * 16 + g * 4 + rr;
                int o = wo * 64 + ot * 16 + lr;
                if (m < M_TOK) {
                    unsigned int u = cvt_pk_bf16(acc[fo][ot][rr], acc[fo][ot][rr]);
                    outp[(size_t)m * DM + o] = (unsigned short)u;
                }
            }
}

// ---------------- attention + W_out(global-stream) + residual + layernorm ----------------
// (r13-17 structure; Qp partials now bf16 — shift-convert on load)
__global__ __launch_bounds__(256) void k_attn(const unsigned short* __restrict__ Qp,
                                              const float* __restrict__ Qb,
                                              const float* __restrict__ Kenc,
                                              const float* __restrict__ Venc,
                                              const float* __restrict__ xin,
                                              const float* __restrict__ Wout,
                                              const float* __restrict__ gamma,
                                              const float* __restrict__ beta,
                                              float* __restrict__ out) {
    __shared__ float Qs[12][132];
    __shared__ float Ks[12][132];
    __shared__ float Vs[12][132];
    __shared__ float Ss[12][12][8];
    __shared__ float Os[12][132];
    const int t = threadIdx.x;
    const int b = blockIdx.x / NN_;
    const int n = blockIdx.x % NN_;

    for (int e = t; e < 384; e += 256) {
        int row = e >> 5, c4 = e & 31;
        size_t mrow = (size_t)(b * NP + row) * NN_ + n;
        f32x4 q = *reinterpret_cast<const f32x4*>(&Qb[mrow * DM + c4 * 4]);
        #pragma unroll
        for (int k = 0; k < KSPLIT; ++k) {
            const unsigned int* pp = reinterpret_cast<const unsigned int*>(
                &Qp[((size_t)k * M_PAD + mrow) * DM + c4 * 4]);
            unsigned int p0 = pp[0], p1 = pp[1];
            q[0] += __uint_as_float(p0 << 16);
            q[1] += __uint_as_float(p0 & 0xffff0000u);
            q[2] += __uint_as_float(p1 << 16);
            q[3] += __uint_as_float(p1 & 0xffff0000u);
        }
        *reinterpret_cast<f32x4*>(&Qs[row][c4 * 4]) = q;
        *reinterpret_cast<f32x4*>(&Ks[row][c4 * 4]) =
            *reinterpret_cast<const f32x4*>(&Kenc[mrow * DM + c4 * 4]);
        *reinterpret_cast<f32x4*>(&Vs[row][c4 * 4]) =
            *reinterpret_cast<const f32x4*>(&Venc[mrow * DM + c4 * 4]);
    }
    __syncthreads();
    if (t < 144) {
        int q = t / 12, p = t % 12;
        #pragma unroll
        for (int hh = 0; hh < 8; ++hh) {
            const f32x4* qv = reinterpret_cast<const f32x4*>(&Qs[q][hh * 16]);
            const f32x4* kv = reinterpret_cast<const f32x4*>(&Ks[p][hh * 16]);
            float s = 0.0f;
            #pragma unroll
            for (int c = 0; c < 4; ++c) {
                f32x4 a = qv[c], bb = kv[c];
                s += a[0] * bb[0] + a[1] * bb[1] + a[2] * bb[2] + a[3] * bb[3];
            }
            Ss[q][p][hh] = s * 0.25f;
        }
    }
    __syncthreads();
    if (t < 96) {
        int q = t >> 3, hh = t & 7;
        float mx = -1e30f;
        #pragma unroll
        for (int p = 0; p < 12; ++p) mx = fmaxf(mx, Ss[q][p][hh]);
        float ev[12]; float sum = 0.0f;
        #pragma unroll
        for (int p = 0; p < 12; ++p) { ev[p] = __expf(Ss[q][p][hh] - mx); sum += ev[p]; }
        float inv = 1.0f / sum;
        #pragma unroll
        for (int p = 0; p < 12; ++p) Ss[q][p][hh] = ev[p] * inv;
    }
    __syncthreads();
    #pragma unroll
    for (int i = 0; i < 6; ++i) {
        int e = i * 256 + t;
        int q = e >> 7, hk = e & 127, hh = hk >> 4;
        float acc = 0.0f;
        #pragma unroll
        for (int p = 0; p < 12; ++p) acc += Ss[q][p][hh] * Vs[p][hk];
        Os[q][hk] = acc;
    }
    __syncthreads();
    {
        const int o  = t & 127;
        const int qh = (t >> 7) * 6;
        const f32x4* wrow = reinterpret_cast<const f32x4*>(&Wout[(size_t)o * DM]);
        float pacc[6] = {0, 0, 0, 0, 0, 0};
        for (int c = 0; c < 32; ++c) {
            f32x4 wv = wrow[c];
            #pragma unroll
            for (int qq = 0; qq < 6; ++qq) {
                f32x4 ov = *reinterpret_cast<const f32x4*>(&Os[qh + qq][c * 4]);
                pacc[qq] += wv[0] * ov[0] + wv[1] * ov[1] + wv[2] * ov[2] + wv[3] * ov[3];
            }
        }
        #pragma unroll
        for (int qq = 0; qq < 6; ++qq) {
            size_t mrow = (size_t)(b * NP + qh + qq) * NN_ + n;
            Qs[qh + qq][o] = pacc[qq] + xin[mrow * DM + o];
        }
    }
    __syncthreads();
    const int wv_ = t >> 6, ll = t & 63;
    for (int rq = wv_; rq < 12; rq += 4) {
        float v0 = Qs[rq][ll], v1 = Qs[rq][ll + 64];
        float s = v0 + v1, ss = v0 * v0 + v1 * v1;
        #pragma unroll
        for (int msk = 1; msk < 64; msk <<= 1) {
            s += __shfl_xor(s, msk, 64);
            ss += __shfl_xor(ss, msk, 64);
        }
        float mu = s * (1.0f / 128.0f);
        float var = ss * (1.0f / 128.0f) - mu * mu;
        float rs = rsqrtf(var + 1e-5f);
        size_t mrow = (size_t)(b * NP + rq) * NN_ + n;
        out[mrow * DM + ll]      = (v0 - mu) * rs * gamma[ll] + beta[ll];
        out[mrow * DM + ll + 64] = (v1 - mu) * rs * gamma[ll + 64] + beta[ll + 64];
    }
}

// ---------------- launcher ----------------
extern "C" void kernel_launch(void* const* d_in, const int* in_sizes, int n_in,
                              void* d_out, int out_size, void* d_ws, size_t ws_size,
                              hipStream_t stream) {
    const float* xin   = (const float*)d_in[0];
    const float* Kenc  = (const float*)d_in[1];
    const float* Venc  = (const float*)d_in[2];
    const float* ct    = (const float*)d_in[3];
    const float* W1    = (const float*)d_in[4];
    const float* b1    = (const float*)d_in[5];
    const float* W2    = (const float*)d_in[6];
    const float* b2    = (const float*)d_in[7];
    const float* Wout  = (const float*)d_in[8];
    const float* gamma = (const float*)d_in[9];
    const float* beta  = (const float*)d_in[10];
    float* out = (float*)d_out;

    char* ws = (char*)d_ws;
    unsigned short* W2b = (unsigned short*)(ws);                  //  8,388,608 B
    float* xT  = (float*)(ws + 8388608);                          //  5,111,808 B (128 x 9984)
    float* hb  = (float*)(ws + 13500416);                         // 10,223,616 B (9984 x 256)
    float* Qb  = (float*)(ws + 23724032);                         //  5,111,808 B
    unsigned short* Qp = (unsigned short*)(ws + 28835840);        // 20,447,232 B (8 x 9984 x 128 bf16)

    hipLaunchKernelGGL(k_prep, dim3(3374), dim3(256), 0, stream,
                       W2, W2b, xin, xT, ct, W1, b1, b2, hb, Qb);
    hipLaunchKernelGGL(k_gemm, dim3(504), dim3(256), 0, stream, W2b, hb, xT, Qp);
    hipLaunchKernelGGL(k_attn, dim3(828), dim3(256), 0, stream, Qp, Qb, Kenc, Venc,
                       xin, Wout, gamma, beta, out);
}

// Round 19
// 138.672 us; speedup vs baseline: 1.0859x; 1.0666x over previous
//
#include <hip/hip_runtime.h>
#include <hip/hip_bf16.h>

// Problem constants
#define NB    4
#define NP    12          // P1 == P == 12
#define NN_   207
#define DM    128         // d_model
#define DHID  256
#define M_TOK 9936        // NB*NP*NN_
#define M_PAD 9984        // padded to 78*128 (xT / hb / Qp row space)
#define KSPLIT 8          // j-splits (j-chunk = 32)

typedef float        f32x4 __attribute__((ext_vector_type(4)));
typedef unsigned int u32x4 __attribute__((ext_vector_type(4)));
typedef __bf16       bf16x8 __attribute__((ext_vector_type(8)));

static __device__ __forceinline__ unsigned int pk_bf2(float a, float b) {
    __hip_bfloat16 ba = __float2bfloat16(a);
    __hip_bfloat16 bb = __float2bfloat16(b);
    unsigned short ua = *reinterpret_cast<unsigned short*>(&ba);
    unsigned short ub = *reinterpret_cast<unsigned short*>(&bb);
    return (unsigned int)ua | ((unsigned int)ub << 16);
}
// hardware packed f32->bf16 (RNE), 1 instr per 2 elements (no builtin on gfx950).
static __device__ __forceinline__ unsigned int cvt_pk_bf16(float lo, float hi) {
    unsigned int r;
    asm("v_cvt_pk_bf16_f32 %0, %1, %2" : "=v"(r) : "v"(lo), "v"(hi));
    return r;
}

// ---------------- prep: W2->bf16 | transpose x->xT | meta-MFMA (h f32, Qb) ----------
// blocks [0,2048): cvt_w2; [2048,3296): transpose; [3296,3452): meta (64 tokens/block —
// split from 128 to double CU coverage of the longest prep phase).
__global__ __launch_bounds__(256) void k_prep(const float* __restrict__ W2,
                                              unsigned short* __restrict__ W2b,
                                              const float* __restrict__ x,
                                              float* __restrict__ xT,
                                              const float* __restrict__ ct,
                                              const float* __restrict__ W1,
                                              const float* __restrict__ b1,
                                              const float* __restrict__ b2,
                                              float* __restrict__ hb,
                                              float* __restrict__ Qb) {
    const int t = threadIdx.x;
    const int bid = blockIdx.x;
    if (bid < 2048) {
        int i = bid * 256 + t;
        const f32x4* in = reinterpret_cast<const f32x4*>(W2);
        f32x4 v0 = in[2 * i], v1 = in[2 * i + 1];
        u32x4 o;
        o[0] = pk_bf2(v0[0], v0[1]);
        o[1] = pk_bf2(v0[2], v0[3]);
        o[2] = pk_bf2(v1[0], v1[1]);
        o[3] = pk_bf2(v1[2], v1[3]);
        reinterpret_cast<u32x4*>(W2b)[i] = o;
        return;
    }
    if (bid < 3296) {
        __shared__ float tile[32][33];
        const int b = bid - 2048;
        const int bm = b >> 2;
        const int bd = b & 3;
        const int m0 = bm * 32, d0 = bd * 32;
        #pragma unroll
        for (int i = 0; i < 4; ++i) {
            int e = i * 256 + t;
            int lm = e >> 5, ld = e & 31;
            int m = m0 + lm;
            tile[lm][ld] = (m < M_TOK) ? x[(size_t)m * DM + d0 + ld] : 0.0f;
        }
        __syncthreads();
        #pragma unroll
        for (int i = 0; i < 4; ++i) {
            int e = i * 256 + t;
            int ld = e >> 5, lm = e & 31;
            xT[(size_t)(d0 + ld) * M_PAD + m0 + lm] = tile[lm][ld];
        }
        return;
    }
    // ---- meta: 64 tokens per block ----
    __shared__ unsigned short AB[64 * 128];   // 16KB: ct_bf then x_bf, swizzled
    __shared__ unsigned short WB[64 * 128];   // 16KB: W1b / b2b chunk, swizzled
    const int m0 = (bid - 3296) * 64;
    const int w = t >> 6, l = t & 63;
    const int lr = l & 15, g = l >> 4;

    #pragma unroll
    for (int it = 0; it < 4; ++it) {
        int r = (t >> 4) + it * 16;
        int gg = t & 15;
        int m = m0 + r;
        f32x4 a = (f32x4)(0.0f), b = (f32x4)(0.0f);
        if (m < M_TOK) {
            a = *reinterpret_cast<const f32x4*>(&ct[(size_t)m * DM + gg * 8]);
            b = *reinterpret_cast<const f32x4*>(&ct[(size_t)m * DM + gg * 8 + 4]);
        }
        u32x4 pk;
        pk[0] = pk_bf2(a[0], a[1]); pk[1] = pk_bf2(a[2], a[3]);
        pk[2] = pk_bf2(b[0], b[1]); pk[3] = pk_bf2(b[2], b[3]);
        *reinterpret_cast<u32x4*>(&AB[r * 128 + ((gg ^ (r & 7)) * 8)]) = pk;
    }

    for (int jc = 0; jc < 4; ++jc) {
        __syncthreads();
        #pragma unroll
        for (int it = 0; it < 4; ++it) {
            int r = (t >> 4) + it * 16;
            int gg = t & 15;
            const float* src = &W1[(size_t)(jc * 64 + r) * DM + gg * 8];
            f32x4 a = *reinterpret_cast<const f32x4*>(src);
            f32x4 b = *reinterpret_cast<const f32x4*>(src + 4);
            u32x4 pk;
            pk[0] = pk_bf2(a[0], a[1]); pk[1] = pk_bf2(a[2], a[3]);
            pk[2] = pk_bf2(b[0], b[1]); pk[3] = pk_bf2(b[2], b[3]);
            *reinterpret_cast<u32x4*>(&WB[r * 128 + ((gg ^ (r & 7)) * 8)]) = pk;
        }
        __syncthreads();
        f32x4 acc[4];
        #pragma unroll
        for (int jf = 0; jf < 4; ++jf) acc[jf] = (f32x4)(0.0f);
        #pragma unroll
        for (int ks = 0; ks < 4; ++ks) {
            int rowA = w * 16 + lr;
            bf16x8 A1 = *reinterpret_cast<const bf16x8*>(
                &AB[rowA * 128 + (((ks * 4 + g) ^ (rowA & 7)) * 8)]);
            #pragma unroll
            for (int jf = 0; jf < 4; ++jf) {
                int row = jf * 16 + lr;
                bf16x8 B1 = *reinterpret_cast<const bf16x8*>(
                    &WB[row * 128 + (((ks * 4 + g) ^ (row & 7)) * 8)]);
                acc[jf] = __builtin_amdgcn_mfma_f32_16x16x32_bf16(A1, B1, acc[jf], 0, 0, 0);
            }
        }
        #pragma unroll
        for (int jf = 0; jf < 4; ++jf) {
            int j = jc * 64 + jf * 16 + lr;
            float bv = b1[j];
            #pragma unroll
            for (int rr = 0; rr < 4; ++rr) {
                int m = m0 + w * 16 + g * 4 + rr;
                if (m < M_TOK)
                    hb[(size_t)m * DHID + j] = fmaxf(acc[jf][rr] + bv, 0.0f);
            }
        }
    }

    __syncthreads();
    #pragma unroll
    for (int it = 0; it < 4; ++it) {
        int r = (t >> 4) + it * 16;
        int gg = t & 15;
        int m = m0 + r;
        f32x4 a = (f32x4)(0.0f), b = (f32x4)(0.0f);
        if (m < M_TOK) {
            a = *reinterpret_cast<const f32x4*>(&x[(size_t)m * DM + gg * 8]);
            b = *reinterpret_cast<const f32x4*>(&x[(size_t)m * DM + gg * 8 + 4]);
        }
        u32x4 pk;
        pk[0] = pk_bf2(a[0], a[1]); pk[1] = pk_bf2(a[2], a[3]);
        pk[2] = pk_bf2(b[0], b[1]); pk[3] = pk_bf2(b[2], b[3]);
        *reinterpret_cast<u32x4*>(&AB[r * 128 + ((gg ^ (r & 7)) * 8)]) = pk;
    }
    for (int oc = 0; oc < 2; ++oc) {
        #pragma unroll
        for (int it = 0; it < 4; ++it) {
            int r = (t >> 4) + it * 16;
            int gg = t & 15;
            const float* src = &b2[(size_t)(oc * 64 + r) * DM + gg * 8];
            f32x4 a = *reinterpret_cast<const f32x4*>(src);
            f32x4 b = *reinterpret_cast<const f32x4*>(src + 4);
            u32x4 pk;
            pk[0] = pk_bf2(a[0], a[1]); pk[1] = pk_bf2(a[2], a[3]);
            pk[2] = pk_bf2(b[0], b[1]); pk[3] = pk_bf2(b[2], b[3]);
            *reinterpret_cast<u32x4*>(&WB[r * 128 + ((gg ^ (r & 7)) * 8)]) = pk;
        }
        __syncthreads();
        f32x4 acc[4];
        #pragma unroll
        for (int of = 0; of < 4; ++of) acc[of] = (f32x4)(0.0f);
        #pragma unroll
        for (int ks = 0; ks < 4; ++ks) {
            int rowA = w * 16 + lr;
            bf16x8 A1 = *reinterpret_cast<const bf16x8*>(
                &AB[rowA * 128 + (((ks * 4 + g) ^ (rowA & 7)) * 8)]);
            #pragma unroll
            for (int of = 0; of < 4; ++of) {
                int row = of * 16 + lr;
                bf16x8 B1 = *reinterpret_cast<const bf16x8*>(
                    &WB[row * 128 + (((ks * 4 + g) ^ (row & 7)) * 8)]);
                acc[of] = __builtin_amdgcn_mfma_f32_16x16x32_bf16(A1, B1, acc[of], 0, 0, 0);
            }
        }
        #pragma unroll
        for (int of = 0; of < 4; ++of) {
            int o = oc * 64 + of * 16 + lr;
            #pragma unroll
            for (int rr = 0; rr < 4; ++rr) {
                int m = m0 + w * 16 + g * 4 + rr;
                if (m < M_TOK) Qb[(size_t)m * DM + o] = acc[of][rr];
            }
        }
        __syncthreads();
    }
}

// ---------------- bilinear GEMM, m-tile 160, 2x2 waves, d-unroll 2, bf16 partials -----
// (r17/18 structure — verified; Qp now laid out [m][kid][o] so attn's 8-partial gather
// touches ONE 2KB row instead of 8 pages 2.5MB apart)
__global__ __launch_bounds__(256, 2) void k_gemm(const unsigned short* __restrict__ W2b,
                                                 const float* __restrict__ hbuf,
                                                 const float* __restrict__ xT,
                                                 unsigned short* __restrict__ Qp) {
    __shared__ unsigned short As[2][10240];   // [buf][slice(5120) x2] 20KB per buf
    __shared__ unsigned short Bs[2][8192];    // [buf][slice(4096) x2] 16KB per buf
    const int t = threadIdx.x;
    const int kid = blockIdx.x & 7;      // j-split -> XCD (round-robin dispatch)
    const int mb  = blockIdx.x >> 3;     // 0..62
    const int m0 = mb * 160;
    const int j0 = kid * 32;
    const int w = t >> 6, l = t & 63;
    const int wo  = w & 1;               // o-half: wave owns o in [wo*64, +64)
    const int wmi = w >> 1;              // m-half: wave owns m in [wmi*80, +80)
    const int lr = l & 15, g = l >> 4;

    // staging: base row rA = t>>2, chunk c = t&3
    const int rA = t >> 2;
    const int c  = t & 3;
    const bool has3 = (t < 128);         // wave-uniform (waves 0,1)
    const int aw = rA * 32 + ((c ^ ((rA >> 1) & 3)) * 8);   // +2048 per 64-row band

    // h fragments (constant over d)
    const float* h1p = &hbuf[(size_t)(m0 + rA) * DHID + j0 + c * 8];
    const float* h2p = &hbuf[(size_t)(m0 + 64 + rA) * DHID + j0 + c * 8];
    const f32x4 h1a = *reinterpret_cast<const f32x4*>(h1p);
    const f32x4 h1b = *reinterpret_cast<const f32x4*>(h1p + 4);
    const f32x4 h2a = *reinterpret_cast<const f32x4*>(h2p);
    const f32x4 h2b = *reinterpret_cast<const f32x4*>(h2p + 4);
    f32x4 h3a = (f32x4)(0.0f), h3b = (f32x4)(0.0f);
    if (has3) {
        const float* h3p = &hbuf[(size_t)(m0 + 128 + rA) * DHID + j0 + c * 8];
        h3a = *reinterpret_cast<const f32x4*>(h3p);
        h3b = *reinterpret_cast<const f32x4*>(h3p + 4);
    }

    f32x4 acc[5][4];
    #pragma unroll
    for (int fo = 0; fo < 5; ++fo)
        #pragma unroll
        for (int ot = 0; ot < 4; ++ot) acc[fo][ot] = (f32x4)(0.0f);

    // B sources: o-rows rA and rA+64; element (o*128+d)*256 + j
    const unsigned short* bp1 = W2b + (size_t)rA * 32768 + j0 + c * 8;
    const unsigned short* bp2 = bp1 + (size_t)64 * 32768;
    const float* xp = xT + m0 + rA;

    // read offsets: A row = wmi*80 + fo*16 + lr (+5120 slice1); B row = wo*64 + ot*16 + lr
    const int rswz = (g ^ ((lr >> 1) & 3)) * 8;
    const int aBase = wmi * 2560 + lr * 32 + rswz;     // + fo*512
    const int bBase = wo * 2048 + lr * 32 + rswz;      // + ot*512

    // STAGE one d-slice into (BUF, slice offsets SA/SB)
#define STAGE(BUF, SA, SB, BV1, BV2, XV1, XV2, XV3) do {               \
        u32x4 a_;                                                      \
        a_[0] = cvt_pk_bf16((XV1) * h1a[0], (XV1) * h1a[1]);           \
        a_[1] = cvt_pk_bf16((XV1) * h1a[2], (XV1) * h1a[3]);           \
        a_[2] = cvt_pk_bf16((XV1) * h1b[0], (XV1) * h1b[1]);           \
        a_[3] = cvt_pk_bf16((XV1) * h1b[2], (XV1) * h1b[3]);           \
        *reinterpret_cast<u32x4*>(&As[BUF][(SA) + aw]) = a_;           \
        a_[0] = cvt_pk_bf16((XV2) * h2a[0], (XV2) * h2a[1]);           \
        a_[1] = cvt_pk_bf16((XV2) * h2a[2], (XV2) * h2a[3]);           \
        a_[2] = cvt_pk_bf16((XV2) * h2b[0], (XV2) * h2b[1]);           \
        a_[3] = cvt_pk_bf16((XV2) * h2b[2], (XV2) * h2b[3]);           \
        *reinterpret_cast<u32x4*>(&As[BUF][(SA) + aw + 2048]) = a_;    \
        if (has3) {                                                    \
            a_[0] = cvt_pk_bf16((XV3) * h3a[0], (XV3) * h3a[1]);       \
            a_[1] = cvt_pk_bf16((XV3) * h3a[2], (XV3) * h3a[3]);       \
            a_[2] = cvt_pk_bf16((XV3) * h3b[0], (XV3) * h3b[1]);       \
            a_[3] = cvt_pk_bf16((XV3) * h3b[2], (XV3) * h3b[3]);       \
            *reinterpret_cast<u32x4*>(&As[BUF][(SA) + aw + 4096]) = a_; \
        }                                                              \
        *reinterpret_cast<u32x4*>(&Bs[BUF][(SB) + aw]) = (BV1);        \
        *reinterpret_cast<u32x4*>(&Bs[BUF][(SB) + aw + 2048]) = (BV2); \
    } while (0)

    // prologue: stage window 0 (d=0 slice0, d=1 slice1) into buf0
    {
        u32x4 bv1 = *reinterpret_cast<const u32x4*>(bp1);
        u32x4 bv2 = *reinterpret_cast<const u32x4*>(bp2);
        STAGE(0, 0, 0, bv1, bv2, xp[0], xp[64], xp[128]);
        bv1 = *reinterpret_cast<const u32x4*>(bp1 + 256);
        bv2 = *reinterpret_cast<const u32x4*>(bp2 + 256);
        STAGE(0, 5120, 4096, bv1, bv2, xp[M_PAD], xp[M_PAD + 64], xp[M_PAD + 128]);
    }
    // prefetch window 1 (d=2,3) into named regs
    u32x4 nb1a = *reinterpret_cast<const u32x4*>(bp1 + 512);
    u32x4 nb2a = *reinterpret_cast<const u32x4*>(bp2 + 512);
    u32x4 nb1b = *reinterpret_cast<const u32x4*>(bp1 + 768);
    u32x4 nb2b = *reinterpret_cast<const u32x4*>(bp2 + 768);
    const float* xq2 = xp + 2 * (size_t)M_PAD;
    const float* xq3 = xp + 3 * (size_t)M_PAD;
    float nx1a = xq2[0], nx2a = xq2[64], nx3a = xq2[128];
    float nx1b = xq3[0], nx2b = xq3[64], nx3b = xq3[128];
    __syncthreads();

    int cur = 0;
    for (int wd = 0; wd < 64; ++wd) {
        u32x4 bfA0 = *reinterpret_cast<const u32x4*>(&Bs[cur][bBase]);
        u32x4 bfA1 = *reinterpret_cast<const u32x4*>(&Bs[cur][bBase + 512]);
        u32x4 bfA2 = *reinterpret_cast<const u32x4*>(&Bs[cur][bBase + 1024]);
        u32x4 bfA3 = *reinterpret_cast<const u32x4*>(&Bs[cur][bBase + 1536]);
        u32x4 bfB0 = *reinterpret_cast<const u32x4*>(&Bs[cur][bBase + 4096]);
        u32x4 bfB1 = *reinterpret_cast<const u32x4*>(&Bs[cur][bBase + 4608]);
        u32x4 bfB2 = *reinterpret_cast<const u32x4*>(&Bs[cur][bBase + 5120]);
        u32x4 bfB3 = *reinterpret_cast<const u32x4*>(&Bs[cur][bBase + 5632]);
        if (wd < 63) {
            STAGE(cur ^ 1, 0, 0, nb1a, nb2a, nx1a, nx2a, nx3a);
            STAGE(cur ^ 1, 5120, 4096, nb1b, nb2b, nx1b, nx2b, nx3b);
        }
        if (wd < 62) {
            const int d4 = 2 * wd + 4, d5 = 2 * wd + 5;
            nb1a = *reinterpret_cast<const u32x4*>(bp1 + (size_t)d4 * 256);
            nb2a = *reinterpret_cast<const u32x4*>(bp2 + (size_t)d4 * 256);
            nb1b = *reinterpret_cast<const u32x4*>(bp1 + (size_t)d5 * 256);
            nb2b = *reinterpret_cast<const u32x4*>(bp2 + (size_t)d5 * 256);
            const float* xq4 = xp + (size_t)d4 * M_PAD;
            const float* xq5 = xp + (size_t)d5 * M_PAD;
            nx1a = xq4[0]; nx2a = xq4[64]; nx3a = xq4[128];
            nx1b = xq5[0]; nx2b = xq5[64]; nx3b = xq5[128];
        }
        __builtin_amdgcn_s_setprio(1);
        #pragma unroll
        for (int fo = 0; fo < 5; ++fo) {
            u32x4 afr = *reinterpret_cast<const u32x4*>(&As[cur][aBase + fo * 512]);
            asm("v_mfma_f32_16x16x32_bf16 %0, %1, %2, %0" : "+v"(acc[fo][0]) : "v"(afr), "v"(bfA0));
            asm("v_mfma_f32_16x16x32_bf16 %0, %1, %2, %0" : "+v"(acc[fo][1]) : "v"(afr), "v"(bfA1));
            asm("v_mfma_f32_16x16x32_bf16 %0, %1, %2, %0" : "+v"(acc[fo][2]) : "v"(afr), "v"(bfA2));
            asm("v_mfma_f32_16x16x32_bf16 %0, %1, %2, %0" : "+v"(acc[fo][3]) : "v"(afr), "v"(bfA3));
        }
        #pragma unroll
        for (int fo = 0; fo < 5; ++fo) {
            u32x4 afr = *reinterpret_cast<const u32x4*>(&As[cur][aBase + 5120 + fo * 512]);
            asm("v_mfma_f32_16x16x32_bf16 %0, %1, %2, %0" : "+v"(acc[fo][0]) : "v"(afr), "v"(bfB0));
            asm("v_mfma_f32_16x16x32_bf16 %0, %1, %2, %0" : "+v"(acc[fo][1]) : "v"(afr), "v"(bfB1));
            asm("v_mfma_f32_16x16x32_bf16 %0, %1, %2, %0" : "+v"(acc[fo][2]) : "v"(afr), "v"(bfB2));
            asm("v_mfma_f32_16x16x32_bf16 %0, %1, %2, %0" : "+v"(acc[fo][3]) : "v"(afr), "v"(bfB3));
        }
        __builtin_amdgcn_s_setprio(0);
        __syncthreads();
        cur ^= 1;
    }
#undef STAGE

    // epilogue: write bf16 partial into [m][kid][o] layout (row stride KSPLIT*DM)
    #pragma unroll
    for (int fo = 0; fo < 5; ++fo)
        #pragma unroll
        for (int ot = 0; ot < 4; ++ot)
            #pragma unroll
            for (int rr = 0; rr < 4; ++rr) {
                int m = m0 + wmi * 80 + fo * 16 + g * 4 + rr;
                int o = wo * 64 + ot * 16 + lr;
                if (m < M_TOK) {
                    unsigned int u = cvt_pk_bf16(acc[fo][ot][rr], acc[fo][ot][rr]);
                    Qp[(size_t)m * (KSPLIT * DM) + kid * DM + o] = (unsigned short)u;
                }
            }
}

// ---------------- attention + W_out(global-stream) + residual + layernorm ----------------
// (Qp partials bf16 in [m][kid][o] layout — 8-partial gather is one 2KB row)
__global__ __launch_bounds__(256) void k_attn(const unsigned short* __restrict__ Qp,
                                              const float* __restrict__ Qb,
                                              const float* __restrict__ Kenc,
                                              const float* __restrict__ Venc,
                                              const float* __restrict__ xin,
                                              const float* __restrict__ Wout,
                                              const float* __restrict__ gamma,
                                              const float* __restrict__ beta,
                                              float* __restrict__ out) {
    __shared__ float Qs[12][132];
    __shared__ float Ks[12][132];
    __shared__ float Vs[12][132];
    __shared__ float Ss[12][12][8];
    __shared__ float Os[12][132];
    const int t = threadIdx.x;
    const int b = blockIdx.x / NN_;
    const int n = blockIdx.x % NN_;

    for (int e = t; e < 384; e += 256) {
        int row = e >> 5, c4 = e & 31;
        size_t mrow = (size_t)(b * NP + row) * NN_ + n;
        f32x4 q = *reinterpret_cast<const f32x4*>(&Qb[mrow * DM + c4 * 4]);
        const unsigned short* qprow = Qp + mrow * (KSPLIT * DM) + c4 * 4;
        #pragma unroll
        for (int k = 0; k < KSPLIT; ++k) {
            const unsigned int* pp = reinterpret_cast<const unsigned int*>(qprow + k * DM);
            unsigned int p0 = pp[0], p1 = pp[1];
            q[0] += __uint_as_float(p0 << 16);
            q[1] += __uint_as_float(p0 & 0xffff0000u);
            q[2] += __uint_as_float(p1 << 16);
            q[3] += __uint_as_float(p1 & 0xffff0000u);
        }
        *reinterpret_cast<f32x4*>(&Qs[row][c4 * 4]) = q;
        *reinterpret_cast<f32x4*>(&Ks[row][c4 * 4]) =
            *reinterpret_cast<const f32x4*>(&Kenc[mrow * DM + c4 * 4]);
        *reinterpret_cast<f32x4*>(&Vs[row][c4 * 4]) =
            *reinterpret_cast<const f32x4*>(&Venc[mrow * DM + c4 * 4]);
    }
    __syncthreads();
    if (t < 144) {
        int q = t / 12, p = t % 12;
        #pragma unroll
        for (int hh = 0; hh < 8; ++hh) {
            const f32x4* qv = reinterpret_cast<const f32x4*>(&Qs[q][hh * 16]);
            const f32x4* kv = reinterpret_cast<const f32x4*>(&Ks[p][hh * 16]);
            float s = 0.0f;
            #pragma unroll
            for (int c = 0; c < 4; ++c) {
                f32x4 a = qv[c], bb = kv[c];
                s += a[0] * bb[0] + a[1] * bb[1] + a[2] * bb[2] + a[3] * bb[3];
            }
            Ss[q][p][hh] = s * 0.25f;
        }
    }
    __syncthreads();
    if (t < 96) {
        int q = t >> 3, hh = t & 7;
        float mx = -1e30f;
        #pragma unroll
        for (int p = 0; p < 12; ++p) mx = fmaxf(mx, Ss[q][p][hh]);
        float ev[12]; float sum = 0.0f;
        #pragma unroll
        for (int p = 0; p < 12; ++p) { ev[p] = __expf(Ss[q][p][hh] - mx); sum += ev[p]; }
        float inv = 1.0f / sum;
        #pragma unroll
        for (int p = 0; p < 12; ++p) Ss[q][p][hh] = ev[p] * inv;
    }
    __syncthreads();
    #pragma unroll
    for (int i = 0; i < 6; ++i) {
        int e = i * 256 + t;
        int q = e >> 7, hk = e & 127, hh = hk >> 4;
        float acc = 0.0f;
        #pragma unroll
        for (int p = 0; p < 12; ++p) acc += Ss[q][p][hh] * Vs[p][hk];
        Os[q][hk] = acc;
    }
    __syncthreads();
    {
        const int o  = t & 127;
        const int qh = (t >> 7) * 6;
        const f32x4* wrow = reinterpret_cast<const f32x4*>(&Wout[(size_t)o * DM]);
        float pacc[6] = {0, 0, 0, 0, 0, 0};
        for (int c = 0; c < 32; ++c) {
            f32x4 wv = wrow[c];
            #pragma unroll
            for (int qq = 0; qq < 6; ++qq) {
                f32x4 ov = *reinterpret_cast<const f32x4*>(&Os[qh + qq][c * 4]);
                pacc[qq] += wv[0] * ov[0] + wv[1] * ov[1] + wv[2] * ov[2] + wv[3] * ov[3];
            }
        }
        #pragma unroll
        for (int qq = 0; qq < 6; ++qq) {
            size_t mrow = (size_t)(b * NP + qh + qq) * NN_ + n;
            Qs[qh + qq][o] = pacc[qq] + xin[mrow * DM + o];
        }
    }
    __syncthreads();
    const int wv_ = t >> 6, ll = t & 63;
    for (int rq = wv_; rq < 12; rq += 4) {
        float v0 = Qs[rq][ll], v1 = Qs[rq][ll + 64];
        float s = v0 + v1, ss = v0 * v0 + v1 * v1;
        #pragma unroll
        for (int msk = 1; msk < 64; msk <<= 1) {
            s += __shfl_xor(s, msk, 64);
            ss += __shfl_xor(ss, msk, 64);
        }
        float mu = s * (1.0f / 128.0f);
        float var = ss * (1.0f / 128.0f) - mu * mu;
        float rs = rsqrtf(var + 1e-5f);
        size_t mrow = (size_t)(b * NP + rq) * NN_ + n;
        out[mrow * DM + ll]      = (v0 - mu) * rs * gamma[ll] + beta[ll];
        out[mrow * DM + ll + 64] = (v1 - mu) * rs * gamma[ll + 64] + beta[ll + 64];
    }
}

// ---------------- launcher ----------------
extern "C" void kernel_launch(void* const* d_in, const int* in_sizes, int n_in,
                              void* d_out, int out_size, void* d_ws, size_t ws_size,
                              hipStream_t stream) {
    const float* xin   = (const float*)d_in[0];
    const float* Kenc  = (const float*)d_in[1];
    const float* Venc  = (const float*)d_in[2];
    const float* ct    = (const float*)d_in[3];
    const float* W1    = (const float*)d_in[4];
    const float* b1    = (const float*)d_in[5];
    const float* W2    = (const float*)d_in[6];
    const float* b2    = (const float*)d_in[7];
    const float* Wout  = (const float*)d_in[8];
    const float* gamma = (const float*)d_in[9];
    const float* beta  = (const float*)d_in[10];
    float* out = (float*)d_out;

    char* ws = (char*)d_ws;
    unsigned short* W2b = (unsigned short*)(ws);                  //  8,388,608 B
    float* xT  = (float*)(ws + 8388608);                          //  5,111,808 B (128 x 9984)
    float* hb  = (float*)(ws + 13500416);                         // 10,223,616 B (9984 x 256)
    float* Qb  = (float*)(ws + 23724032);                         //  5,111,808 B
    unsigned short* Qp = (unsigned short*)(ws + 28835840);        // 20,447,232 B ([m][kid][o] bf16)

    hipLaunchKernelGGL(k_prep, dim3(3452), dim3(256), 0, stream,
                       W2, W2b, xin, xT, ct, W1, b1, b2, hb, Qb);
    hipLaunchKernelGGL(k_gemm, dim3(504), dim3(256), 0, stream, W2b, hb, xT, Qp);
    hipLaunchKernelGGL(k_attn, dim3(828), dim3(256), 0, stream, Qp, Qb, Kenc, Venc,
                       xin, Wout, gamma, beta, out);
}